// Round 1
// baseline (254.836 us; speedup 1.0000x reference)
//
#include <hip/hip_runtime.h>
#include <hip/hip_bf16.h>

typedef __attribute__((ext_vector_type(8))) short bf16x8;
typedef __attribute__((ext_vector_type(4))) short bf16x4;
typedef __attribute__((ext_vector_type(4))) float f32x4;

__device__ inline short f2bf(float f) {
    unsigned u = __builtin_bit_cast(unsigned, f);
    u += 0x7FFF + ((u >> 16) & 1);   // round-to-nearest-even
    return (short)(u >> 16);
}

// ---------------------------------------------------------------------------
// Projection: out = x @ W^T + bias, written as bf16 in [B][H][T][dk] layout.
// z = 0: Q(queries,Wq,bq)  z = 1: K(keys,Wk,bk)  z = 2: V(keys,Wv,bv)
// M=4096 (b*2048+t), N=1024 (h*64+d), K=1024.
// Block: 256 thr = 4 waves (2x2), tile 128x128, wave tile 64x64, BK=32.
// ---------------------------------------------------------------------------
__global__ __launch_bounds__(256) void proj_qkv(
    const float* __restrict__ xq, const float* __restrict__ xk,
    const float* __restrict__ Wq, const float* __restrict__ Wk,
    const float* __restrict__ Wv,
    const float* __restrict__ bq, const float* __restrict__ bk,
    const float* __restrict__ bv,
    short* __restrict__ ws)
{
    const int z = blockIdx.z;
    const float* x    = (z == 0) ? xq : xk;
    const float* W    = (z == 0) ? Wq : (z == 1) ? Wk : Wv;
    const float* bias = (z == 0) ? bq : (z == 1) ? bk : bv;
    short* out = ws + (size_t)z * 4194304;   // 4096*1024 elems per matrix

    const int m0 = blockIdx.x * 128;
    const int n0 = blockIdx.y * 128;
    const int tid  = threadIdx.x;
    const int lane = tid & 63;
    const int wid  = tid >> 6;
    const int wr = wid >> 1, wc = wid & 1;
    const int l15 = lane & 15, lhi = lane >> 4;

    __shared__ alignas(16) short As[128][40];   // +8 pad, 80B row stride
    __shared__ alignas(16) short Bs[128][40];

    f32x4 acc[4][4] = {};

    for (int k0 = 0; k0 < 1024; k0 += 32) {
        __syncthreads();
#pragma unroll
        for (int it = 0; it < 4; ++it) {
            int idx = tid + it * 256;      // 0..1023
            int row = idx >> 3;            // 0..127
            int c4  = idx & 7;             // 0..7 (float4 within 32 cols)
            float4 va = *(const float4*)&x[(size_t)(m0 + row) * 1024 + k0 + c4 * 4];
            float4 vb = *(const float4*)&W[(size_t)(n0 + row) * 1024 + k0 + c4 * 4];
            bf16x4 sa = { f2bf(va.x), f2bf(va.y), f2bf(va.z), f2bf(va.w) };
            bf16x4 sb = { f2bf(vb.x), f2bf(vb.y), f2bf(vb.z), f2bf(vb.w) };
            *(bf16x4*)&As[row][c4 * 4] = sa;
            *(bf16x4*)&Bs[row][c4 * 4] = sb;
        }
        __syncthreads();

        const int kf = lhi * 8;
        bf16x8 a[4], b[4];
#pragma unroll
        for (int i = 0; i < 4; ++i)
            a[i] = *(const bf16x8*)&As[wr * 64 + i * 16 + l15][kf];
#pragma unroll
        for (int j = 0; j < 4; ++j)
            b[j] = *(const bf16x8*)&Bs[wc * 64 + j * 16 + l15][kf];
#pragma unroll
        for (int i = 0; i < 4; ++i)
#pragma unroll
            for (int j = 0; j < 4; ++j)
                acc[i][j] = __builtin_amdgcn_mfma_f32_16x16x32_bf16(
                    a[i], b[j], acc[i][j], 0, 0, 0);
    }

    // Epilogue: C/D layout col=lane&15, row=(lane>>4)*4+reg  [m89/m91 verified]
#pragma unroll
    for (int i = 0; i < 4; ++i) {
        int mbase = m0 + wr * 64 + i * 16 + lhi * 4;
#pragma unroll
        for (int j = 0; j < 4; ++j) {
            int n = n0 + wc * 64 + j * 16 + l15;
            float bval = bias[n];
            int h = n >> 6, d = n & 63;
#pragma unroll
            for (int r = 0; r < 4; ++r) {
                int m = mbase + r;
                int bb = m >> 11, t = m & 2047;
                out[(((size_t)bb * 16 + h) * 2048 + t) * 64 + d] =
                    f2bf(acc[i][j][r] + bval);
            }
        }
    }
}

// ---------------------------------------------------------------------------
// Flash attention. grid (T/64, B*H), 256 thr = 4 waves, each wave owns 16
// q-rows. KBLK = 64. Mask quirk: mask batch = (b*H+h) % B; post-softmax
// query-axis mask multiply.
// ---------------------------------------------------------------------------
__global__ __launch_bounds__(256) void attn_fwd(
    const short* __restrict__ Qb, const short* __restrict__ Kb,
    const short* __restrict__ Vb, const int* __restrict__ key_mask,
    float* __restrict__ out)
{
    const int qb = blockIdx.x;   // 0..31
    const int bh = blockIdx.y;   // 0..31 (= b*16 + h)
    const int b  = bh >> 4;
    const int h  = bh & 15;
    const int mb = bh & 1;       // (b*H + h) % B, B=2

    const int tid  = threadIdx.x;
    const int lane = tid & 63;
    const int wid  = tid >> 6;
    const int l15  = lane & 15;
    const int lhi  = lane >> 4;

    const size_t base = (size_t)bh * 2048 * 64;
    const int q0 = qb * 64;

    __shared__ alignas(16) short Ks[64][72];      // key tile, row-major [k][d]
    __shared__ alignas(16) short Vt[64][72];      // V transposed [d][k]
    __shared__ alignas(16) short Ps[4][16][72];   // per-wave P tile [q][k]

    // Q fragments live in registers for the whole kernel
    bf16x8 qf[2];
    {
        int qrow = q0 + wid * 16 + l15;
        const short* qp = Qb + base + (size_t)qrow * 64 + lhi * 8;
        qf[0] = *(const bf16x8*)(qp);
        qf[1] = *(const bf16x8*)(qp + 32);
    }

    f32x4 acc[4] = {};
    float mrun[4], lrun[4];
#pragma unroll
    for (int r = 0; r < 4; ++r) { mrun[r] = -1e30f; lrun[r] = 0.f; }

    const float scale = 0.125f;                  // 1/sqrt(64)
    const int* km_row = key_mask + mb * 2048;

    for (int kb = 0; kb < 32; ++kb) {
        const int k0 = kb * 64;
        __syncthreads();   // previous iter's Vt/Ks reads complete
#pragma unroll
        for (int it = 0; it < 2; ++it) {
            int idx = tid + it * 256;   // 0..511
            int row = idx >> 3;         // 0..63  (key index in tile)
            int c8  = idx & 7;          // 8-elem group of d
            bf16x8 kv = *(const bf16x8*)&Kb[base + (size_t)(k0 + row) * 64 + c8 * 8];
            *(bf16x8*)&Ks[row][c8 * 8] = kv;
            bf16x8 vv = *(const bf16x8*)&Vb[base + (size_t)(k0 + row) * 64 + c8 * 8];
#pragma unroll
            for (int j = 0; j < 8; ++j) Vt[c8 * 8 + j][row] = vv[j];
        }
        __syncthreads();

        int kmv[4];
#pragma unroll
        for (int j = 0; j < 4; ++j) kmv[j] = km_row[k0 + j * 16 + l15];

        // S = Q K^T * scale : per wave 16 q-rows x 64 keys
        f32x4 s[4];
#pragma unroll
        for (int j = 0; j < 4; ++j) {
            f32x4 sa = {};
#pragma unroll
            for (int ks = 0; ks < 2; ++ks) {
                bf16x8 bfr = *(const bf16x8*)&Ks[j * 16 + l15][ks * 32 + lhi * 8];
                sa = __builtin_amdgcn_mfma_f32_16x16x32_bf16(qf[ks], bfr, sa, 0, 0, 0);
            }
            s[j] = sa * scale;
        }

        // online softmax (state per reg = per q-row; rows=(lhi*4+r))
        float mnew[4], fac[4];
#pragma unroll
        for (int r = 0; r < 4; ++r) {
            float mx = fmaxf(fmaxf(s[0][r], s[1][r]), fmaxf(s[2][r], s[3][r]));
            mx = fmaxf(mx, __shfl_xor(mx, 1));
            mx = fmaxf(mx, __shfl_xor(mx, 2));
            mx = fmaxf(mx, __shfl_xor(mx, 4));
            mx = fmaxf(mx, __shfl_xor(mx, 8));
            mnew[r] = fmaxf(mrun[r], mx);
            fac[r]  = __expf(mrun[r] - mnew[r]);
        }

        float p[4][4];
#pragma unroll
        for (int j = 0; j < 4; ++j)
#pragma unroll
            for (int r = 0; r < 4; ++r)
                p[j][r] = kmv[j] ? __expf(s[j][r] - mnew[r]) : 0.f;

#pragma unroll
        for (int r = 0; r < 4; ++r) {
            float su = p[0][r] + p[1][r] + p[2][r] + p[3][r];
            su += __shfl_xor(su, 1);
            su += __shfl_xor(su, 2);
            su += __shfl_xor(su, 4);
            su += __shfl_xor(su, 8);
            lrun[r] = lrun[r] * fac[r] + su;
            mrun[r] = mnew[r];
        }
#pragma unroll
        for (int n = 0; n < 4; ++n)
#pragma unroll
            for (int r = 0; r < 4; ++r)
                acc[n][r] *= fac[r];

        // P -> LDS (D-layout -> A-layout redistribution)
#pragma unroll
        for (int j = 0; j < 4; ++j)
#pragma unroll
            for (int r = 0; r < 4; ++r)
                Ps[wid][lhi * 4 + r][j * 16 + l15] = f2bf(p[j][r]);

        __syncthreads();   // make Ps visible (also keeps waves together)

        // O += P V
#pragma unroll
        for (int ks = 0; ks < 2; ++ks) {
            bf16x8 pa = *(const bf16x8*)&Ps[wid][l15][ks * 32 + lhi * 8];
#pragma unroll
            for (int n = 0; n < 4; ++n) {
                bf16x8 vfr = *(const bf16x8*)&Vt[n * 16 + l15][ks * 32 + lhi * 8];
                acc[n] = __builtin_amdgcn_mfma_f32_16x16x32_bf16(pa, vfr, acc[n], 0, 0, 0);
            }
        }
    }

    // epilogue: normalize, apply query-axis mask, write f32 out (B,T,H*dk)
#pragma unroll
    for (int r = 0; r < 4; ++r) {
        int q = q0 + wid * 16 + lhi * 4 + r;
        float qmf = (float)km_row[q] / lrun[r];
#pragma unroll
        for (int n = 0; n < 4; ++n)
            out[((size_t)b * 2048 + q) * 1024 + h * 64 + n * 16 + l15] =
                acc[n][r] * qmf;
    }
}

extern "C" void kernel_launch(void* const* d_in, const int* in_sizes, int n_in,
                              void* d_out, int out_size, void* d_ws, size_t ws_size,
                              hipStream_t stream) {
    const float* queries = (const float*)d_in[0];
    const float* keys    = (const float*)d_in[1];
    const int*   key_mask= (const int*)d_in[2];
    const float* Wq = (const float*)d_in[3];
    const float* bq = (const float*)d_in[4];
    const float* Wk = (const float*)d_in[5];
    const float* bk = (const float*)d_in[6];
    const float* Wv = (const float*)d_in[7];
    const float* bv = (const float*)d_in[8];
    float* out = (float*)d_out;

    short* qkv = (short*)d_ws;   // 3 * 4096*1024 bf16 = 24 MB

    proj_qkv<<<dim3(32, 8, 3), 256, 0, stream>>>(
        queries, keys, Wq, Wk, Wv, bq, bk, bv, qkv);

    attn_fwd<<<dim3(32, 32), 256, 0, stream>>>(
        qkv, qkv + 4194304, qkv + 2 * 4194304, key_mask, out);
}

// Round 2
// 153.963 us; speedup vs baseline: 1.6552x; 1.6552x over previous
//
#include <hip/hip_runtime.h>
#include <hip/hip_bf16.h>

typedef __attribute__((ext_vector_type(8))) short bf16x8;
typedef __attribute__((ext_vector_type(4))) short bf16x4;
typedef __attribute__((ext_vector_type(4))) float f32x4;
typedef __attribute__((ext_vector_type(16))) float f32x16;
typedef __attribute__((ext_vector_type(4))) unsigned u32x4;

__device__ inline short f2bf(float f) {
    unsigned u = __builtin_bit_cast(unsigned, f);
    u += 0x7FFF + ((u >> 16) & 1);   // round-to-nearest-even
    return (short)(u >> 16);
}

// ---------------------------------------------------------------------------
// Projection: out = x @ W^T + bias, bf16.
// z=0: Q -> [bh][t][64]   z=1: K -> [bh][t][64]   z=2: V -> [bh][64][t] (T!)
// M=4096, N=1024, K=1024. 256 thr = 4 waves (2x2), tile 128x128, BK=32.
// ---------------------------------------------------------------------------
__global__ __launch_bounds__(256) void proj_qkv(
    const float* __restrict__ xq, const float* __restrict__ xk,
    const float* __restrict__ Wq, const float* __restrict__ Wk,
    const float* __restrict__ Wv,
    const float* __restrict__ bq, const float* __restrict__ bk,
    const float* __restrict__ bv,
    short* __restrict__ ws)
{
    const int z = blockIdx.z;
    const float* x    = (z == 0) ? xq : xk;
    const float* W    = (z == 0) ? Wq : (z == 1) ? Wk : Wv;
    const float* bias = (z == 0) ? bq : (z == 1) ? bk : bv;
    short* out = ws + (size_t)z * 4194304;

    const int m0 = blockIdx.x * 128;
    const int n0 = blockIdx.y * 128;
    const int tid  = threadIdx.x;
    const int lane = tid & 63;
    const int wid  = tid >> 6;
    const int wr = wid >> 1, wc = wid & 1;
    const int l15 = lane & 15, lhi = lane >> 4;

    __shared__ alignas(16) short As[128][40];
    __shared__ alignas(16) short Bs[128][40];

    f32x4 acc[4][4] = {};

    for (int k0 = 0; k0 < 1024; k0 += 32) {
        __syncthreads();
#pragma unroll
        for (int it = 0; it < 4; ++it) {
            int idx = tid + it * 256;
            int row = idx >> 3;
            int c4  = idx & 7;
            float4 va = *(const float4*)&x[(size_t)(m0 + row) * 1024 + k0 + c4 * 4];
            float4 vb = *(const float4*)&W[(size_t)(n0 + row) * 1024 + k0 + c4 * 4];
            bf16x4 sa = { f2bf(va.x), f2bf(va.y), f2bf(va.z), f2bf(va.w) };
            bf16x4 sb = { f2bf(vb.x), f2bf(vb.y), f2bf(vb.z), f2bf(vb.w) };
            *(bf16x4*)&As[row][c4 * 4] = sa;
            *(bf16x4*)&Bs[row][c4 * 4] = sb;
        }
        __syncthreads();

        const int kf = lhi * 8;
        bf16x8 a[4], b[4];
#pragma unroll
        for (int i = 0; i < 4; ++i)
            a[i] = *(const bf16x8*)&As[wr * 64 + i * 16 + l15][kf];
#pragma unroll
        for (int j = 0; j < 4; ++j)
            b[j] = *(const bf16x8*)&Bs[wc * 64 + j * 16 + l15][kf];
#pragma unroll
        for (int i = 0; i < 4; ++i)
#pragma unroll
            for (int j = 0; j < 4; ++j)
                acc[i][j] = __builtin_amdgcn_mfma_f32_16x16x32_bf16(
                    a[i], b[j], acc[i][j], 0, 0, 0);
    }

    if (z == 2) {
        // V transposed: [bh][d][t]; 4 consecutive t per reg quartet -> 8B store
#pragma unroll
        for (int i = 0; i < 4; ++i) {
            int mbase = m0 + wr * 64 + i * 16 + lhi * 4;
            int bb = mbase >> 11, t0 = mbase & 2047;
#pragma unroll
            for (int j = 0; j < 4; ++j) {
                int n = n0 + wc * 64 + j * 16 + l15;
                float bval = bias[n];
                int h = n >> 6, d = n & 63;
                bf16x4 pk;
#pragma unroll
                for (int r = 0; r < 4; ++r) pk[r] = f2bf(acc[i][j][r] + bval);
                *(bf16x4*)&out[(((size_t)bb * 16 + h) * 64 + d) * 2048 + t0] = pk;
            }
        }
    } else {
#pragma unroll
        for (int i = 0; i < 4; ++i) {
            int mbase = m0 + wr * 64 + i * 16 + lhi * 4;
#pragma unroll
            for (int j = 0; j < 4; ++j) {
                int n = n0 + wc * 64 + j * 16 + l15;
                float bval = bias[n];
                int h = n >> 6, d = n & 63;
#pragma unroll
                for (int r = 0; r < 4; ++r) {
                    int m = mbase + r;
                    int bb = m >> 11, t = m & 2047;
                    out[(((size_t)bb * 16 + h) * 2048 + t) * 64 + d] =
                        f2bf(acc[i][j][r] + bval);
                }
            }
        }
    }
}

// ---------------------------------------------------------------------------
// Flash attention, 32x32x16 MFMA, swapped operands (S^T = K Q^T, O^T = V^T P^T)
// so softmax state is lane-local (lane l31 owns q-row q0+l31).
// grid (16, 32): 4 waves x 32 q-rows = 128 q/block. KVBLK=64, dbuf LDS.
// K LDS [64][64] + V^T LDS [64][64], XOR-swizzled (g ^= row&7) via
// pre-swizzled global_load_lds source (linear dest, swizzled read).
// ---------------------------------------------------------------------------
__global__ __launch_bounds__(256) void attn_fwd(
    const short* __restrict__ Qb, const short* __restrict__ Kb,
    const short* __restrict__ Vtb, const int* __restrict__ key_mask,
    float* __restrict__ out)
{
    const int bh = blockIdx.y;
    const int b  = bh >> 4;
    const int h  = bh & 15;
    const int mb = bh & 1;            // (b*H + h) % B, B=2
    const int tid  = threadIdx.x;
    const int lane = tid & 63;
    const int wid  = tid >> 6;
    const int l31  = lane & 31;
    const int hi   = lane >> 5;

    const size_t base = (size_t)bh * 2048 * 64;
    const int q0 = blockIdx.x * 128 + wid * 32;

    __shared__ alignas(16) short KVs[2][8192];   // [buf][ K 64x64 | V^T 64x64 ]
    __shared__ alignas(16) float Ld[4][32 * 68]; // per-wave epilogue transpose

    const int* km_row = key_mask + mb * 2048;

    // Q fragments (B-operand): lane l31 = q, k = hi*8+e
    bf16x8 qf[4];
#pragma unroll
    for (int ks = 0; ks < 4; ++ks)
        qf[ks] = *(const bf16x8*)&Qb[base + (size_t)(q0 + l31) * 64 + ks * 16 + hi * 8];

    // staging source pointers: LDS[row][g] = SRC[row][g ^ (row&7)]
    const int lrow = lane >> 3;                  // 0..7
    const int lcol = (lane & 7) ^ (lrow & 7);    // swizzled 16B group
    const short* srcK[2];
    const short* srcV[2];
#pragma unroll
    for (int i = 0; i < 2; ++i) {
        int r0 = wid * 16 + i * 8;
        srcK[i] = Kb  + base + (size_t)(r0 + lrow) * 64   + lcol * 8;
        srcV[i] = Vtb + base + (size_t)(r0 + lrow) * 2048 + lcol * 8;
    }

    f32x16 acc[2];
#pragma unroll
    for (int n = 0; n < 2; ++n)
#pragma unroll
        for (int r = 0; r < 16; ++r) acc[n][r] = 0.f;
    float mrun = -1e30f, lrun = 0.f;
    const float SC = 0.18033688f;    // 0.125 * log2(e)

#define STAGE(T, BUF)                                                          \
    {                                                                          \
        _Pragma("unroll")                                                      \
        for (int i = 0; i < 2; ++i) {                                          \
            int r0 = wid * 16 + i * 8;                                         \
            __builtin_amdgcn_global_load_lds(                                  \
                (const __attribute__((address_space(1))) unsigned int*)        \
                    (srcK[i] + (size_t)(T) * 4096),                            \
                (__attribute__((address_space(3))) unsigned int*)              \
                    &KVs[BUF][r0 * 64],                                        \
                16, 0, 0);                                                     \
            __builtin_amdgcn_global_load_lds(                                  \
                (const __attribute__((address_space(1))) unsigned int*)        \
                    (srcV[i] + (size_t)(T) * 64),                              \
                (__attribute__((address_space(3))) unsigned int*)              \
                    &KVs[BUF][4096 + r0 * 64],                                 \
                16, 0, 0);                                                     \
        }                                                                      \
    }

    STAGE(0, 0);

    for (int t = 0; t < 32; ++t) {
        const int buf = t & 1;
        const int k0 = t * 64;
        __syncthreads();                 // tile t staged; buf^1 free to overwrite
        if (t < 31) STAGE(t + 1, buf ^ 1);

        // key-mask int4 loads (uniform per half-wave, L1-resident)
        const int4* kp = (const int4*)(km_row + k0);
        int4 mk[2][4];
#pragma unroll
        for (int s = 0; s < 2; ++s)
#pragma unroll
            for (int g = 0; g < 4; ++g)
                mk[s][g] = kp[s * 8 + g * 2 + hi];

        // S^T = K * Q^T : D[key][q], col(lane&31)=q, row=(r&3)+8*(r>>2)+4*hi
        f32x16 sacc[2];
#pragma unroll
        for (int s = 0; s < 2; ++s) {
#pragma unroll
            for (int r = 0; r < 16; ++r) sacc[s][r] = 0.f;
#pragma unroll
            for (int ks = 0; ks < 4; ++ks) {
                int row = s * 32 + l31;
                int xg = ((2 * ks + hi) ^ (row & 7)) * 8;
                bf16x8 kf = *(const bf16x8*)&KVs[buf][row * 64 + xg];
                sacc[s] = __builtin_amdgcn_mfma_f32_32x32x16_bf16(
                    kf, qf[ks], sacc[s], 0, 0, 0);
            }
        }

        // online softmax, fully lane-local except one shfl_xor(32)
        float mx = -1e30f;
#pragma unroll
        for (int s = 0; s < 2; ++s)
#pragma unroll
            for (int r = 0; r < 16; ++r) mx = fmaxf(mx, sacc[s][r]);
        mx = fmaxf(mx, __shfl_xor(mx, 32));
        float mnew = fmaxf(mrun, mx);
        float fac  = __builtin_amdgcn_exp2f((mrun - mnew) * SC);
        float msc  = mnew * SC;

        float p[2][16];
        float sum = 0.f;
#pragma unroll
        for (int s = 0; s < 2; ++s)
#pragma unroll
            for (int g = 0; g < 4; ++g)
#pragma unroll
                for (int c = 0; c < 4; ++c) {
                    int r = g * 4 + c;
                    float pe = __builtin_amdgcn_exp2f(sacc[s][r] * SC - msc);
                    int mval = (c == 0) ? mk[s][g].x : (c == 1) ? mk[s][g].y
                             : (c == 2) ? mk[s][g].z : mk[s][g].w;
                    pe = mval ? pe : 0.f;
                    p[s][r] = pe;
                    sum += pe;
                }
        sum += __shfl_xor(sum, 32);
        lrun = lrun * fac + sum;
        mrun = mnew;
#pragma unroll
        for (int n = 0; n < 2; ++n)
#pragma unroll
            for (int r = 0; r < 16; ++r) acc[n][r] *= fac;

        // pack P to bf16 pairs: pk2[s][g] covers keys s*32 + 8g + 4hi + {0..3}
        unsigned pk2[2][4][2];
#pragma unroll
        for (int s = 0; s < 2; ++s)
#pragma unroll
            for (int g = 0; g < 4; ++g)
#pragma unroll
                for (int w = 0; w < 2; ++w) {
                    unsigned d;
                    asm("v_cvt_pk_bf16_f32 %0, %1, %2"
                        : "=v"(d)
                        : "v"(p[s][g * 4 + 2 * w]), "v"(p[s][g * 4 + 2 * w + 1]));
                    pk2[s][g][w] = d;
                }

        // O^T += V^T * P^T : per kstep build B-frag via permlane32_swap
#pragma unroll
        for (int s = 0; s < 2; ++s)
#pragma unroll
            for (int kk = 0; kk < 2; ++kk) {
                unsigned w0 = pk2[s][2 * kk][0],     w1 = pk2[s][2 * kk][1];
                unsigned w2 = pk2[s][2 * kk + 1][0], w3 = pk2[s][2 * kk + 1][1];
                asm("v_permlane32_swap_b32 %0, %1" : "+v"(w0), "+v"(w2));
                asm("v_permlane32_swap_b32 %0, %1" : "+v"(w1), "+v"(w3));
                u32x4 fv = { w0, w1, w2, w3 };
                bf16x8 pf = __builtin_bit_cast(bf16x8, fv);
                int kq = s * 2 + kk;     // contraction step over 64 keys
#pragma unroll
                for (int n = 0; n < 2; ++n) {
                    int row = n * 32 + l31;
                    int xg = ((2 * kq + hi) ^ (row & 7)) * 8;
                    bf16x8 vf = *(const bf16x8*)&KVs[buf][4096 + row * 64 + xg];
                    acc[n] = __builtin_amdgcn_mfma_f32_32x32x16_bf16(
                        vf, pf, acc[n], 0, 0, 0);
                }
            }
    }
#undef STAGE

    // epilogue: normalize + query-mask, transpose via per-wave LDS, coalesced out
    float qn = (float)km_row[q0 + l31] / lrun;
    float* Lw = Ld[wid];
#pragma unroll
    for (int n = 0; n < 2; ++n)
#pragma unroll
        for (int r = 0; r < 16; ++r) {
            int d = n * 32 + (r & 3) + 8 * (r >> 2) + 4 * hi;
            Lw[l31 * 68 + d] = acc[n][r] * qn;
        }
    const int l15 = lane & 15, lq = lane >> 4;
#pragma unroll
    for (int rep = 0; rep < 8; ++rep) {
        int qr = rep * 4 + lq;
        f32x4 v = *(const f32x4*)&Lw[qr * 68 + l15 * 4];
        *(f32x4*)&out[((size_t)b * 2048 + q0 + qr) * 1024 + h * 64 + l15 * 4] = v;
    }
}

extern "C" void kernel_launch(void* const* d_in, const int* in_sizes, int n_in,
                              void* d_out, int out_size, void* d_ws, size_t ws_size,
                              hipStream_t stream) {
    const float* queries = (const float*)d_in[0];
    const float* keys    = (const float*)d_in[1];
    const int*   key_mask= (const int*)d_in[2];
    const float* Wq = (const float*)d_in[3];
    const float* bq = (const float*)d_in[4];
    const float* Wk = (const float*)d_in[5];
    const float* bk = (const float*)d_in[6];
    const float* Wv = (const float*)d_in[7];
    const float* bv = (const float*)d_in[8];
    float* out = (float*)d_out;

    short* qkv = (short*)d_ws;   // Q | K | V^T, 3 * 4096*1024 bf16 = 24 MB

    proj_qkv<<<dim3(32, 8, 3), 256, 0, stream>>>(
        queries, keys, Wq, Wk, Wv, bq, bk, bv, qkv);

    attn_fwd<<<dim3(16, 32), 256, 0, stream>>>(
        qkv, qkv + 4194304, qkv + 2 * 4194304, key_mask, out);
}

// Round 3
// 139.705 us; speedup vs baseline: 1.8241x; 1.1021x over previous
//
#include <hip/hip_runtime.h>
#include <hip/hip_bf16.h>

typedef __attribute__((ext_vector_type(8))) short bf16x8;
typedef __attribute__((ext_vector_type(4))) short bf16x4;
typedef __attribute__((ext_vector_type(4))) float f32x4;
typedef __attribute__((ext_vector_type(16))) float f32x16;
typedef __attribute__((ext_vector_type(4))) unsigned u32x4;

__device__ inline short f2bf(float f) {
    unsigned u = __builtin_bit_cast(unsigned, f);
    u += 0x7FFF + ((u >> 16) & 1);   // round-to-nearest-even
    return (short)(u >> 16);
}

// ws layout (units: shorts/bf16):
//   0        : Q   [32][2048][64]   (proj out)
//   4194304  : K   [32][2048][64]   (proj out)
//   8388608  : V^T [32][64][2048]   (proj out)
//   12582912 : xq_bf16 [4096][1024]
//   16777216 : xk_bf16 [4096][1024]
//   20971520 : Wq_bf16 [1024][1024]; +1M: Wk; +2M: Wv
// total 23M shorts = 46 MB

// ---------------------------------------------------------------------------
// f32 -> bf16 convert (memory-bound). 11264 blocks x 256 thr x 4 floats.
// ---------------------------------------------------------------------------
__global__ __launch_bounds__(256) void cvt_bf16(
    const float* __restrict__ xq, const float* __restrict__ xk,
    const float* __restrict__ Wq, const float* __restrict__ Wk,
    const float* __restrict__ Wv, short* __restrict__ ws)
{
    const int blk = blockIdx.x;
    int seg, local;
    if (blk < 4096)      { seg = 0; local = blk; }
    else if (blk < 8192) { seg = 1; local = blk - 4096; }
    else                 { seg = 2 + ((blk - 8192) >> 10); local = (blk - 8192) & 1023; }
    const float* src = (seg == 0) ? xq : (seg == 1) ? xk
                     : (seg == 2) ? Wq : (seg == 3) ? Wk : Wv;
    const size_t dstoff = (seg == 0) ? 12582912u : (seg == 1) ? 16777216u
                        : 20971520u + (size_t)(seg - 2) * 1048576u;
    const size_t idx = (size_t)local * 1024 + threadIdx.x * 4;
    float4 v = *(const float4*)&src[idx];
    bf16x4 o = { f2bf(v.x), f2bf(v.y), f2bf(v.z), f2bf(v.w) };
    *(bf16x4*)&ws[dstoff + idx] = o;
}

// ---------------------------------------------------------------------------
// Projection GEMM (bf16): out = x @ W^T + bias.
// z=0: Q -> [bh][t][64]   z=1: K -> [bh][t][64]   z=2: V -> [bh][64][t]
// M=4096, N=1024, K=1024. 256 thr (4 waves 2x2), tile 128x128, BK=32.
// global_load_lds width-16 staging, dbuf, ONE barrier per K-step
// (next-tile loads issued after the barrier fly under the MFMAs).
// ---------------------------------------------------------------------------
__global__ __launch_bounds__(256) void proj_gemm(
    short* __restrict__ ws, const float* __restrict__ bq,
    const float* __restrict__ bk, const float* __restrict__ bv)
{
    const int z = blockIdx.z;
    const short* A  = ws + ((z == 0) ? 12582912u : 16777216u);
    const short* Bw = ws + 20971520u + (size_t)z * 1048576u;
    const float* bias = (z == 0) ? bq : (z == 1) ? bk : bv;
    short* out = ws + (size_t)z * 4194304u;

    const int m0 = blockIdx.x * 128;
    const int n0 = blockIdx.y * 128;
    const int tid  = threadIdx.x;
    const int lane = tid & 63;
    const int wid  = tid >> 6;
    const int wr = wid >> 1, wc = wid & 1;
    const int l15 = lane & 15, lhi = lane >> 4;

    __shared__ alignas(16) short SM[17408];   // dbuf staging 32KB; epilogue 34.8KB

    // per-lane staging sources: lane l covers row (l>>2), 16B group (l&3)
    const int srow = wid * 32 + (lane >> 2);
    const int scol = (lane & 3) * 8;
    const short* aSrc = A  + (size_t)(m0 + srow) * 1024 + scol;
    const short* bSrc = Bw + (size_t)(n0 + srow) * 1024 + scol;

#define PSTAGE(T, BUF) do {                                                    \
    _Pragma("unroll")                                                          \
    for (int i_ = 0; i_ < 2; ++i_) {                                           \
        __builtin_amdgcn_global_load_lds(                                      \
            (const __attribute__((address_space(1))) unsigned*)                \
                (aSrc + (T) * 32 + i_ * 16384),                                \
            (__attribute__((address_space(3))) unsigned*)                      \
                &SM[(BUF) * 8192 + (wid * 32 + i_ * 16) * 32], 16, 0, 0);      \
        __builtin_amdgcn_global_load_lds(                                      \
            (const __attribute__((address_space(1))) unsigned*)                \
                (bSrc + (T) * 32 + i_ * 16384),                                \
            (__attribute__((address_space(3))) unsigned*)                      \
                &SM[(BUF) * 8192 + 4096 + (wid * 32 + i_ * 16) * 32], 16, 0, 0);\
    } } while (0)

    f32x4 acc[4][4] = {};

    PSTAGE(0, 0);
    for (int t = 0; t < 32; ++t) {
        const int buf = t & 1;
        __syncthreads();                    // drains vmcnt -> tile t visible
        if (t < 31) PSTAGE(t + 1, buf ^ 1); // in flight under the MFMAs

        const short* SA = &SM[buf * 8192];
        const short* SB = SA + 4096;
        bf16x8 a[4], b[4];
#pragma unroll
        for (int i = 0; i < 4; ++i)
            a[i] = *(const bf16x8*)&SA[(wr * 64 + i * 16 + l15) * 32 + lhi * 8];
#pragma unroll
        for (int j = 0; j < 4; ++j)
            b[j] = *(const bf16x8*)&SB[(wc * 64 + j * 16 + l15) * 32 + lhi * 8];

        if (z == 2) {
            // acc: col(l15)=n, row(lhi*4+r)=m  -> m contiguous per lane
#pragma unroll
            for (int i = 0; i < 4; ++i)
#pragma unroll
                for (int j = 0; j < 4; ++j)
                    acc[i][j] = __builtin_amdgcn_mfma_f32_16x16x32_bf16(
                        a[i], b[j], acc[i][j], 0, 0, 0);
        } else {
            // swapped: col(l15)=m, row(lhi*4+r)=n -> n contiguous per lane
#pragma unroll
            for (int i = 0; i < 4; ++i)
#pragma unroll
                for (int j = 0; j < 4; ++j)
                    acc[i][j] = __builtin_amdgcn_mfma_f32_16x16x32_bf16(
                        b[j], a[i], acc[i][j], 0, 0, 0);
        }
    }
#undef PSTAGE

    // ---- epilogue: bias + pack, transpose via LDS, 16B coalesced stores ----
    __syncthreads();                        // all frag reads of SM done
    if (z == 2) {
        // SM as Cn[n][136]: row=n, col=m (pad 136 shorts)
#pragma unroll
        for (int i = 0; i < 4; ++i) {
            int mm = wr * 64 + i * 16 + lhi * 4;
#pragma unroll
            for (int j = 0; j < 4; ++j) {
                int nn = wc * 64 + j * 16 + l15;
                float bval = bias[n0 + nn];
                bf16x4 pk = { f2bf(acc[i][j][0] + bval), f2bf(acc[i][j][1] + bval),
                              f2bf(acc[i][j][2] + bval), f2bf(acc[i][j][3] + bval) };
                *(bf16x4*)&SM[nn * 136 + mm] = pk;
            }
        }
    } else {
        // SM as Cs[m][136]: row=m, col=n
#pragma unroll
        for (int i = 0; i < 4; ++i) {
            int mm = wr * 64 + i * 16 + l15;
#pragma unroll
            for (int j = 0; j < 4; ++j) {
                int nnb = wc * 64 + j * 16 + lhi * 4;
                float4 bw = *(const float4*)&bias[n0 + nnb];
                bf16x4 pk = { f2bf(acc[i][j][0] + bw.x), f2bf(acc[i][j][1] + bw.y),
                              f2bf(acc[i][j][2] + bw.z), f2bf(acc[i][j][3] + bw.w) };
                *(bf16x4*)&SM[mm * 136 + nnb] = pk;
            }
        }
    }
    __syncthreads();

    const int bb = m0 >> 11;            // batch (tiles never cross T=2048)
    const int mt = m0 & 2047;
#pragma unroll
    for (int p = 0; p < 8; ++p) {
        int id = p * 256 + tid;
        int rr = id >> 4;               // LDS row
        int g  = id & 15;               // 16B group in row
        bf16x8 v = *(const bf16x8*)&SM[rr * 136 + g * 8];
        if (z == 2) {
            int nn = n0 + rr, h = nn >> 6, d = nn & 63;
            *(bf16x8*)&out[(((size_t)(bb * 16 + h)) * 64 + d) * 2048 + mt + g * 8] = v;
        } else {
            int nn = n0 + g * 8, h = nn >> 6, d = nn & 63;
            *(bf16x8*)&out[(((size_t)(bb * 16 + h)) * 2048 + mt + rr) * 64 + d] = v;
        }
    }
}

// ---------------------------------------------------------------------------
// Flash attention (unchanged from R2): 32x32x16 MFMA, swapped operands,
// lane-local softmax, XOR-swizzled K/V^T staging via global_load_lds, dbuf.
// ---------------------------------------------------------------------------
__global__ __launch_bounds__(256) void attn_fwd(
    const short* __restrict__ Qb, const short* __restrict__ Kb,
    const short* __restrict__ Vtb, const int* __restrict__ key_mask,
    float* __restrict__ out)
{
    const int bh = blockIdx.y;
    const int b  = bh >> 4;
    const int h  = bh & 15;
    const int mb = bh & 1;            // (b*H + h) % B, B=2
    const int tid  = threadIdx.x;
    const int lane = tid & 63;
    const int wid  = tid >> 6;
    const int l31  = lane & 31;
    const int hi   = lane >> 5;

    const size_t base = (size_t)bh * 2048 * 64;
    const int q0 = blockIdx.x * 128 + wid * 32;

    __shared__ alignas(16) short KVs[2][8192];   // [buf][ K 64x64 | V^T 64x64 ]
    __shared__ alignas(16) float Ld[4][32 * 68]; // per-wave epilogue transpose

    const int* km_row = key_mask + mb * 2048;

    bf16x8 qf[4];
#pragma unroll
    for (int ks = 0; ks < 4; ++ks)
        qf[ks] = *(const bf16x8*)&Qb[base + (size_t)(q0 + l31) * 64 + ks * 16 + hi * 8];

    const int lrow = lane >> 3;
    const int lcol = (lane & 7) ^ (lrow & 7);
    const short* srcK[2];
    const short* srcV[2];
#pragma unroll
    for (int i = 0; i < 2; ++i) {
        int r0 = wid * 16 + i * 8;
        srcK[i] = Kb  + base + (size_t)(r0 + lrow) * 64   + lcol * 8;
        srcV[i] = Vtb + base + (size_t)(r0 + lrow) * 2048 + lcol * 8;
    }

    f32x16 acc[2];
#pragma unroll
    for (int n = 0; n < 2; ++n)
#pragma unroll
        for (int r = 0; r < 16; ++r) acc[n][r] = 0.f;
    float mrun = -1e30f, lrun = 0.f;
    const float SC = 0.18033688f;    // 0.125 * log2(e)

#define STAGE(T, BUF)                                                          \
    {                                                                          \
        _Pragma("unroll")                                                      \
        for (int i = 0; i < 2; ++i) {                                          \
            int r0 = wid * 16 + i * 8;                                         \
            __builtin_amdgcn_global_load_lds(                                  \
                (const __attribute__((address_space(1))) unsigned int*)        \
                    (srcK[i] + (size_t)(T) * 4096),                            \
                (__attribute__((address_space(3))) unsigned int*)              \
                    &KVs[BUF][r0 * 64],                                        \
                16, 0, 0);                                                     \
            __builtin_amdgcn_global_load_lds(                                  \
                (const __attribute__((address_space(1))) unsigned int*)        \
                    (srcV[i] + (size_t)(T) * 64),                              \
                (__attribute__((address_space(3))) unsigned int*)              \
                    &KVs[BUF][4096 + r0 * 64],                                 \
                16, 0, 0);                                                     \
        }                                                                      \
    }

    STAGE(0, 0);

    for (int t = 0; t < 32; ++t) {
        const int buf = t & 1;
        const int k0 = t * 64;
        __syncthreads();
        if (t < 31) STAGE(t + 1, buf ^ 1);

        const int4* kp = (const int4*)(km_row + k0);
        int4 mk[2][4];
#pragma unroll
        for (int s = 0; s < 2; ++s)
#pragma unroll
            for (int g = 0; g < 4; ++g)
                mk[s][g] = kp[s * 8 + g * 2 + hi];

        f32x16 sacc[2];
#pragma unroll
        for (int s = 0; s < 2; ++s) {
#pragma unroll
            for (int r = 0; r < 16; ++r) sacc[s][r] = 0.f;
#pragma unroll
            for (int ks = 0; ks < 4; ++ks) {
                int row = s * 32 + l31;
                int xg = ((2 * ks + hi) ^ (row & 7)) * 8;
                bf16x8 kf = *(const bf16x8*)&KVs[buf][row * 64 + xg];
                sacc[s] = __builtin_amdgcn_mfma_f32_32x32x16_bf16(
                    kf, qf[ks], sacc[s], 0, 0, 0);
            }
        }

        float mx = -1e30f;
#pragma unroll
        for (int s = 0; s < 2; ++s)
#pragma unroll
            for (int r = 0; r < 16; ++r) mx = fmaxf(mx, sacc[s][r]);
        mx = fmaxf(mx, __shfl_xor(mx, 32));
        float mnew = fmaxf(mrun, mx);
        float fac  = __builtin_amdgcn_exp2f((mrun - mnew) * SC);
        float msc  = mnew * SC;

        float p[2][16];
        float sum = 0.f;
#pragma unroll
        for (int s = 0; s < 2; ++s)
#pragma unroll
            for (int g = 0; g < 4; ++g)
#pragma unroll
                for (int c = 0; c < 4; ++c) {
                    int r = g * 4 + c;
                    float pe = __builtin_amdgcn_exp2f(sacc[s][r] * SC - msc);
                    int mval = (c == 0) ? mk[s][g].x : (c == 1) ? mk[s][g].y
                             : (c == 2) ? mk[s][g].z : mk[s][g].w;
                    pe = mval ? pe : 0.f;
                    p[s][r] = pe;
                    sum += pe;
                }
        sum += __shfl_xor(sum, 32);
        lrun = lrun * fac + sum;
        mrun = mnew;
#pragma unroll
        for (int n = 0; n < 2; ++n)
#pragma unroll
            for (int r = 0; r < 16; ++r) acc[n][r] *= fac;

        unsigned pk2[2][4][2];
#pragma unroll
        for (int s = 0; s < 2; ++s)
#pragma unroll
            for (int g = 0; g < 4; ++g)
#pragma unroll
                for (int w = 0; w < 2; ++w) {
                    unsigned d;
                    asm("v_cvt_pk_bf16_f32 %0, %1, %2"
                        : "=v"(d)
                        : "v"(p[s][g * 4 + 2 * w]), "v"(p[s][g * 4 + 2 * w + 1]));
                    pk2[s][g][w] = d;
                }

#pragma unroll
        for (int s = 0; s < 2; ++s)
#pragma unroll
            for (int kk = 0; kk < 2; ++kk) {
                unsigned w0 = pk2[s][2 * kk][0],     w1 = pk2[s][2 * kk][1];
                unsigned w2 = pk2[s][2 * kk + 1][0], w3 = pk2[s][2 * kk + 1][1];
                asm("v_permlane32_swap_b32 %0, %1" : "+v"(w0), "+v"(w2));
                asm("v_permlane32_swap_b32 %0, %1" : "+v"(w1), "+v"(w3));
                u32x4 fv = { w0, w1, w2, w3 };
                bf16x8 pf = __builtin_bit_cast(bf16x8, fv);
                int kq = s * 2 + kk;
#pragma unroll
                for (int n = 0; n < 2; ++n) {
                    int row = n * 32 + l31;
                    int xg = ((2 * kq + hi) ^ (row & 7)) * 8;
                    bf16x8 vf = *(const bf16x8*)&KVs[buf][4096 + row * 64 + xg];
                    acc[n] = __builtin_amdgcn_mfma_f32_32x32x16_bf16(
                        vf, pf, acc[n], 0, 0, 0);
                }
            }
    }
#undef STAGE

    float qn = (float)km_row[q0 + l31] / lrun;
    float* Lw = Ld[wid];
#pragma unroll
    for (int n = 0; n < 2; ++n)
#pragma unroll
        for (int r = 0; r < 16; ++r) {
            int d = n * 32 + (r & 3) + 8 * (r >> 2) + 4 * hi;
            Lw[l31 * 68 + d] = acc[n][r] * qn;
        }
    const int l15 = lane & 15, lq = lane >> 4;
#pragma unroll
    for (int rep = 0; rep < 8; ++rep) {
        int qr = rep * 4 + lq;
        f32x4 v = *(const f32x4*)&Lw[qr * 68 + l15 * 4];
        *(f32x4*)&out[((size_t)b * 2048 + q0 + qr) * 1024 + h * 64 + l15 * 4] = v;
    }
}

extern "C" void kernel_launch(void* const* d_in, const int* in_sizes, int n_in,
                              void* d_out, int out_size, void* d_ws, size_t ws_size,
                              hipStream_t stream) {
    const float* queries = (const float*)d_in[0];
    const float* keys    = (const float*)d_in[1];
    const int*   key_mask= (const int*)d_in[2];
    const float* Wq = (const float*)d_in[3];
    const float* bq = (const float*)d_in[4];
    const float* Wk = (const float*)d_in[5];
    const float* bk = (const float*)d_in[6];
    const float* Wv = (const float*)d_in[7];
    const float* bv = (const float*)d_in[8];
    float* out = (float*)d_out;

    short* ws = (short*)d_ws;   // 46 MB used

    cvt_bf16<<<11264, 256, 0, stream>>>(queries, keys, Wq, Wk, Wv, ws);

    proj_gemm<<<dim3(32, 8, 3), 256, 0, stream>>>(ws, bq, bk, bv);

    attn_fwd<<<dim3(16, 32), 256, 0, stream>>>(
        ws, ws + 4194304, ws + 2 * 4194304, key_mask, out);
}

// Round 5
// 129.194 us; speedup vs baseline: 1.9725x; 1.0814x over previous
//
#include <hip/hip_runtime.h>
#include <hip/hip_bf16.h>

typedef __attribute__((ext_vector_type(8))) short bf16x8;
typedef __attribute__((ext_vector_type(4))) short bf16x4;
typedef __attribute__((ext_vector_type(4))) float f32x4;
typedef __attribute__((ext_vector_type(16))) float f32x16;
typedef __attribute__((ext_vector_type(4))) unsigned u32x4;

__device__ inline short f2bf(float f) {
    unsigned u = __builtin_bit_cast(unsigned, f);
    u += 0x7FFF + ((u >> 16) & 1);   // round-to-nearest-even
    return (short)(u >> 16);
}

// ws layout (units: shorts/bf16):
//   0        : Q   [32][2048][64]
//   4194304  : K   [32][2048][64]
//   8388608  : V^T [32][64][2048]
//   12582912 : xq_bf16 [4096][1024]
//   16777216 : xk_bf16 [4096][1024]
//   20971520 : Wq_bf16 [1024][1024]; +1M: Wk; +2M: Wv
//   24117248 : mask bias f32[2][2048] (= 0 or -1e9), 16KB

// ---------------------------------------------------------------------------
// f32 -> bf16 convert (memory-bound) + mask-bias build (block 11264).
// ---------------------------------------------------------------------------
__global__ __launch_bounds__(256) void cvt_bf16(
    const float* __restrict__ xq, const float* __restrict__ xk,
    const float* __restrict__ Wq, const float* __restrict__ Wk,
    const float* __restrict__ Wv, const int* __restrict__ key_mask,
    short* __restrict__ ws)
{
    const int blk = blockIdx.x;
    if (blk >= 11264) {
        float* bias = (float*)(ws + 24117248u);
        const int i0 = threadIdx.x * 4;
#pragma unroll
        for (int p = 0; p < 4; ++p) {
            int idx = p * 1024 + i0;          // 0..4095 = mb*2048 + k
            int4 m = *(const int4*)&key_mask[idx];
            f32x4 o = { m.x ? 0.f : -1e9f, m.y ? 0.f : -1e9f,
                        m.z ? 0.f : -1e9f, m.w ? 0.f : -1e9f };
            *(f32x4*)&bias[idx] = o;
        }
        return;
    }
    int seg, local;
    if (blk < 4096)      { seg = 0; local = blk; }
    else if (blk < 8192) { seg = 1; local = blk - 4096; }
    else                 { seg = 2 + ((blk - 8192) >> 10); local = (blk - 8192) & 1023; }
    const float* src = (seg == 0) ? xq : (seg == 1) ? xk
                     : (seg == 2) ? Wq : (seg == 3) ? Wk : Wv;
    const size_t dstoff = (seg == 0) ? 12582912u : (seg == 1) ? 16777216u
                        : 20971520u + (size_t)(seg - 2) * 1048576u;
    const size_t idx = (size_t)local * 1024 + threadIdx.x * 4;
    float4 v = *(const float4*)&src[idx];
    bf16x4 o = { f2bf(v.x), f2bf(v.y), f2bf(v.z), f2bf(v.w) };
    *(bf16x4*)&ws[dstoff + idx] = o;
}

// ---------------------------------------------------------------------------
// Projection GEMM (bf16): out = x @ W^T + bias. (unchanged)
// z=0: Q -> [bh][t][64]   z=1: K -> [bh][t][64]   z=2: V -> [bh][64][t]
// ---------------------------------------------------------------------------
__global__ __launch_bounds__(256) void proj_gemm(
    short* __restrict__ ws, const float* __restrict__ bq,
    const float* __restrict__ bk, const float* __restrict__ bv)
{
    const int z = blockIdx.z;
    const short* A  = ws + ((z == 0) ? 12582912u : 16777216u);
    const short* Bw = ws + 20971520u + (size_t)z * 1048576u;
    const float* bias = (z == 0) ? bq : (z == 1) ? bk : bv;
    short* out = ws + (size_t)z * 4194304u;

    const int m0 = blockIdx.x * 128;
    const int n0 = blockIdx.y * 128;
    const int tid  = threadIdx.x;
    const int lane = tid & 63;
    const int wid  = tid >> 6;
    const int wr = wid >> 1, wc = wid & 1;
    const int l15 = lane & 15, lhi = lane >> 4;

    __shared__ alignas(16) short SM[17408];

    const int srow = wid * 32 + (lane >> 2);
    const int scol = (lane & 3) * 8;
    const short* aSrc = A  + (size_t)(m0 + srow) * 1024 + scol;
    const short* bSrc = Bw + (size_t)(n0 + srow) * 1024 + scol;

#define PSTAGE(T, BUF) do {                                                    \
    _Pragma("unroll")                                                          \
    for (int i_ = 0; i_ < 2; ++i_) {                                           \
        __builtin_amdgcn_global_load_lds(                                      \
            (const __attribute__((address_space(1))) unsigned*)                \
                (aSrc + (T) * 32 + i_ * 16384),                                \
            (__attribute__((address_space(3))) unsigned*)                      \
                &SM[(BUF) * 8192 + (wid * 32 + i_ * 16) * 32], 16, 0, 0);      \
        __builtin_amdgcn_global_load_lds(                                      \
            (const __attribute__((address_space(1))) unsigned*)                \
                (bSrc + (T) * 32 + i_ * 16384),                                \
            (__attribute__((address_space(3))) unsigned*)                      \
                &SM[(BUF) * 8192 + 4096 + (wid * 32 + i_ * 16) * 32], 16, 0, 0);\
    } } while (0)

    f32x4 acc[4][4] = {};

    PSTAGE(0, 0);
    for (int t = 0; t < 32; ++t) {
        const int buf = t & 1;
        __syncthreads();
        if (t < 31) PSTAGE(t + 1, buf ^ 1);

        const short* SA = &SM[buf * 8192];
        const short* SB = SA + 4096;
        bf16x8 a[4], b[4];
#pragma unroll
        for (int i = 0; i < 4; ++i)
            a[i] = *(const bf16x8*)&SA[(wr * 64 + i * 16 + l15) * 32 + lhi * 8];
#pragma unroll
        for (int j = 0; j < 4; ++j)
            b[j] = *(const bf16x8*)&SB[(wc * 64 + j * 16 + l15) * 32 + lhi * 8];

        if (z == 2) {
#pragma unroll
            for (int i = 0; i < 4; ++i)
#pragma unroll
                for (int j = 0; j < 4; ++j)
                    acc[i][j] = __builtin_amdgcn_mfma_f32_16x16x32_bf16(
                        a[i], b[j], acc[i][j], 0, 0, 0);
        } else {
#pragma unroll
            for (int i = 0; i < 4; ++i)
#pragma unroll
                for (int j = 0; j < 4; ++j)
                    acc[i][j] = __builtin_amdgcn_mfma_f32_16x16x32_bf16(
                        b[j], a[i], acc[i][j], 0, 0, 0);
        }
    }
#undef PSTAGE

    __syncthreads();
    if (z == 2) {
#pragma unroll
        for (int i = 0; i < 4; ++i) {
            int mm = wr * 64 + i * 16 + lhi * 4;
#pragma unroll
            for (int j = 0; j < 4; ++j) {
                int nn = wc * 64 + j * 16 + l15;
                float bval = bias[n0 + nn];
                bf16x4 pk = { f2bf(acc[i][j][0] + bval), f2bf(acc[i][j][1] + bval),
                              f2bf(acc[i][j][2] + bval), f2bf(acc[i][j][3] + bval) };
                *(bf16x4*)&SM[nn * 136 + mm] = pk;
            }
        }
    } else {
#pragma unroll
        for (int i = 0; i < 4; ++i) {
            int mm = wr * 64 + i * 16 + l15;
#pragma unroll
            for (int j = 0; j < 4; ++j) {
                int nnb = wc * 64 + j * 16 + lhi * 4;
                float4 bw = *(const float4*)&bias[n0 + nnb];
                bf16x4 pk = { f2bf(acc[i][j][0] + bw.x), f2bf(acc[i][j][1] + bw.y),
                              f2bf(acc[i][j][2] + bw.z), f2bf(acc[i][j][3] + bw.w) };
                *(bf16x4*)&SM[mm * 136 + nnb] = pk;
            }
        }
    }
    __syncthreads();

    const int bb = m0 >> 11;
    const int mt = m0 & 2047;
#pragma unroll
    for (int p = 0; p < 8; ++p) {
        int id = p * 256 + tid;
        int rr = id >> 4;
        int g  = id & 15;
        bf16x8 v = *(const bf16x8*)&SM[rr * 136 + g * 8];
        if (z == 2) {
            int nn = n0 + rr, h = nn >> 6, d = nn & 63;
            *(bf16x8*)&out[(((size_t)(bb * 16 + h)) * 64 + d) * 2048 + mt + g * 8] = v;
        } else {
            int nn = n0 + g * 8, h = nn >> 6, d = nn & 63;
            *(bf16x8*)&out[(((size_t)(bb * 16 + h)) * 2048 + mt + rr) * 64 + d] = v;
        }
    }
}

// ---------------------------------------------------------------------------
// Flash attention. vs R4: permlane half-reductions REVERTED to shfl_xor(32)
// (bisect: prime suspect for R4's numeric failure). Keeps: LDS union,
// mask-as-C-init bias, defer-max, setprio, grid (bh, qb).
// ---------------------------------------------------------------------------
__device__ inline float pair_max(float v) { return fmaxf(v, __shfl_xor(v, 32)); }
__device__ inline float pair_sum(float v) { return v + __shfl_xor(v, 32); }

__global__ __launch_bounds__(256) void attn_fwd(
    const short* __restrict__ Qb, const short* __restrict__ Kb,
    const short* __restrict__ Vtb, const int* __restrict__ key_mask,
    const float* __restrict__ biasArr, float* __restrict__ out)
{
    const int bh = blockIdx.x;        // bh fastest: same-bh blocks -> same XCD
    const int qb = blockIdx.y;
    const int b  = bh >> 4;
    const int h  = bh & 15;
    const int mb = bh & 1;            // (b*H + h) % B, B=2
    const int tid  = threadIdx.x;
    const int lane = tid & 63;
    const int wid  = tid >> 6;
    const int l31  = lane & 31;
    const int hi   = lane >> 5;

    const size_t base = (size_t)bh * 2048 * 64;
    const int q0 = qb * 128 + wid * 32;

    // LDS union: KVs (2x8192 shorts = 32KB) during loop; Ld (34.8KB) after.
    __shared__ alignas(16) char SMEM[34816];
#define KVS(BUF) ((short*)SMEM + (BUF) * 8192)
    float* Ld = (float*)SMEM;

    const int* km_row = key_mask + mb * 2048;
    const float* bias_row = biasArr + mb * 2048;

    bf16x8 qf[4];
#pragma unroll
    for (int ks = 0; ks < 4; ++ks)
        qf[ks] = *(const bf16x8*)&Qb[base + (size_t)(q0 + l31) * 64 + ks * 16 + hi * 8];

    const int lrow = lane >> 3;
    const int lcol = (lane & 7) ^ (lrow & 7);
    const short* srcK[2];
    const short* srcV[2];
#pragma unroll
    for (int i = 0; i < 2; ++i) {
        int r0 = wid * 16 + i * 8;
        srcK[i] = Kb  + base + (size_t)(r0 + lrow) * 64   + lcol * 8;
        srcV[i] = Vtb + base + (size_t)(r0 + lrow) * 2048 + lcol * 8;
    }

    f32x16 acc[2];
#pragma unroll
    for (int n = 0; n < 2; ++n)
#pragma unroll
        for (int r = 0; r < 16; ++r) acc[n][r] = 0.f;
    float mrun = -1e30f, lrun = 0.f;
    const float SC  = 0.18033688f;    // 0.125 * log2(e)
    const float DTH = 44.3614f;       // 8 / SC : defer-max threshold

#define STAGE(T, BUF)                                                          \
    {                                                                          \
        _Pragma("unroll")                                                      \
        for (int i = 0; i < 2; ++i) {                                          \
            int r0 = wid * 16 + i * 8;                                         \
            __builtin_amdgcn_global_load_lds(                                  \
                (const __attribute__((address_space(1))) unsigned int*)        \
                    (srcK[i] + (size_t)(T) * 4096),                            \
                (__attribute__((address_space(3))) unsigned int*)              \
                    &KVS(BUF)[r0 * 64],                                        \
                16, 0, 0);                                                     \
            __builtin_amdgcn_global_load_lds(                                  \
                (const __attribute__((address_space(1))) unsigned int*)        \
                    (srcV[i] + (size_t)(T) * 64),                              \
                (__attribute__((address_space(3))) unsigned int*)              \
                    &KVS(BUF)[4096 + r0 * 64],                                 \
                16, 0, 0);                                                     \
        }                                                                      \
    }

    STAGE(0, 0);

    for (int t = 0; t < 32; ++t) {
        const int buf = t & 1;
        const int k0 = t * 64;
        __syncthreads();
        if (t < 31) STAGE(t + 1, buf ^ 1);

        // S^T = K*Q^T with C initialized to the mask bias (0 / -1e9).
        const f32x4* bp = (const f32x4*)(bias_row + k0);
        f32x16 sacc[2];
#pragma unroll
        for (int s = 0; s < 2; ++s) {
#pragma unroll
            for (int g = 0; g < 4; ++g) {
                f32x4 bv = bp[s * 8 + g * 2 + hi];
#pragma unroll
                for (int c = 0; c < 4; ++c) sacc[s][g * 4 + c] = bv[c];
            }
        }
        __builtin_amdgcn_s_setprio(1);
#pragma unroll
        for (int s = 0; s < 2; ++s) {
#pragma unroll
            for (int ks = 0; ks < 4; ++ks) {
                int row = s * 32 + l31;
                int xg = ((2 * ks + hi) ^ (row & 7)) * 8;
                bf16x8 kf = *(const bf16x8*)&KVS(buf)[row * 64 + xg];
                sacc[s] = __builtin_amdgcn_mfma_f32_32x32x16_bf16(
                    kf, qf[ks], sacc[s], 0, 0, 0);
            }
        }
        __builtin_amdgcn_s_setprio(0);

        // online softmax with defer-max (THR=8 in exp2 units)
        float mx = sacc[0][0];
#pragma unroll
        for (int s = 0; s < 2; ++s)
#pragma unroll
            for (int r = 0; r < 16; ++r)
                if (s + r) mx = fmaxf(mx, sacc[s][r]);
        mx = pair_max(mx);
        if (!__all(mx <= mrun + DTH)) {
            float mnew = fmaxf(mrun, mx);
            float fac  = __builtin_amdgcn_exp2f((mrun - mnew) * SC);
            lrun *= fac;
#pragma unroll
            for (int n = 0; n < 2; ++n)
#pragma unroll
                for (int r = 0; r < 16; ++r) acc[n][r] *= fac;
            mrun = mnew;
        }
        const float msc = mrun * SC;

        float p[2][16];
        float sum = 0.f;
#pragma unroll
        for (int s = 0; s < 2; ++s)
#pragma unroll
            for (int r = 0; r < 16; ++r) {
                float pe = __builtin_amdgcn_exp2f(sacc[s][r] * SC - msc);
                p[s][r] = pe;
                sum += pe;
            }
        lrun += pair_sum(sum);

        unsigned pk2[2][4][2];
#pragma unroll
        for (int s = 0; s < 2; ++s)
#pragma unroll
            for (int g = 0; g < 4; ++g)
#pragma unroll
                for (int w = 0; w < 2; ++w) {
                    unsigned d;
                    asm("v_cvt_pk_bf16_f32 %0, %1, %2"
                        : "=v"(d)
                        : "v"(p[s][g * 4 + 2 * w]), "v"(p[s][g * 4 + 2 * w + 1]));
                    pk2[s][g][w] = d;
                }

        __builtin_amdgcn_s_setprio(1);
#pragma unroll
        for (int s = 0; s < 2; ++s)
#pragma unroll
            for (int kk = 0; kk < 2; ++kk) {
                unsigned w0 = pk2[s][2 * kk][0],     w1 = pk2[s][2 * kk][1];
                unsigned w2 = pk2[s][2 * kk + 1][0], w3 = pk2[s][2 * kk + 1][1];
                asm("v_permlane32_swap_b32 %0, %1" : "+v"(w0), "+v"(w2));
                asm("v_permlane32_swap_b32 %0, %1" : "+v"(w1), "+v"(w3));
                u32x4 fv = { w0, w1, w2, w3 };
                bf16x8 pf = __builtin_bit_cast(bf16x8, fv);
                int kq = s * 2 + kk;
#pragma unroll
                for (int n = 0; n < 2; ++n) {
                    int row = n * 32 + l31;
                    int xg = ((2 * kq + hi) ^ (row & 7)) * 8;
                    bf16x8 vf = *(const bf16x8*)&KVS(buf)[4096 + row * 64 + xg];
                    acc[n] = __builtin_amdgcn_mfma_f32_32x32x16_bf16(
                        vf, pf, acc[n], 0, 0, 0);
                }
            }
        __builtin_amdgcn_s_setprio(0);
    }
#undef STAGE

    // all waves done with KVs before Ld overwrites it
    __syncthreads();

    float qn = (float)km_row[q0 + l31] / lrun;
    float* Lw = Ld + wid * 2176;
#pragma unroll
    for (int n = 0; n < 2; ++n)
#pragma unroll
        for (int r = 0; r < 16; ++r) {
            int d = n * 32 + (r & 3) + 8 * (r >> 2) + 4 * hi;
            Lw[l31 * 68 + d] = acc[n][r] * qn;
        }
    const int l15 = lane & 15, lq = lane >> 4;
#pragma unroll
    for (int rep = 0; rep < 8; ++rep) {
        int qr = rep * 4 + lq;
        f32x4 v = *(const f32x4*)&Lw[qr * 68 + l15 * 4];
        *(f32x4*)&out[((size_t)b * 2048 + q0 + qr) * 1024 + h * 64 + l15 * 4] = v;
    }
#undef KVS
}

extern "C" void kernel_launch(void* const* d_in, const int* in_sizes, int n_in,
                              void* d_out, int out_size, void* d_ws, size_t ws_size,
                              hipStream_t stream) {
    const float* queries = (const float*)d_in[0];
    const float* keys    = (const float*)d_in[1];
    const int*   key_mask= (const int*)d_in[2];
    const float* Wq = (const float*)d_in[3];
    const float* bq = (const float*)d_in[4];
    const float* Wk = (const float*)d_in[5];
    const float* bk = (const float*)d_in[6];
    const float* Wv = (const float*)d_in[7];
    const float* bv = (const float*)d_in[8];
    float* out = (float*)d_out;

    short* ws = (short*)d_ws;
    const float* biasArr = (const float*)(ws + 24117248u);

    cvt_bf16<<<11265, 256, 0, stream>>>(queries, keys, Wq, Wk, Wv, key_mask, ws);

    proj_gemm<<<dim3(32, 8, 3), 256, 0, stream>>>(ws, bq, bk, bv);

    attn_fwd<<<dim3(32, 16), 256, 0, stream>>>(
        ws, ws + 4194304, ws + 2 * 4194304, key_mask, biasArr, out);
}

// Round 6
// 122.706 us; speedup vs baseline: 2.0768x; 1.0529x over previous
//
#include <hip/hip_runtime.h>
#include <hip/hip_bf16.h>

typedef __attribute__((ext_vector_type(8))) short bf16x8;
typedef __attribute__((ext_vector_type(4))) short bf16x4;
typedef __attribute__((ext_vector_type(4))) float f32x4;
typedef __attribute__((ext_vector_type(16))) float f32x16;
typedef __attribute__((ext_vector_type(4))) unsigned u32x4;

__device__ inline short f2bf(float f) {
    unsigned u = __builtin_bit_cast(unsigned, f);
    u += 0x7FFF + ((u >> 16) & 1);   // round-to-nearest-even
    return (short)(u >> 16);
}

// ws layout (units: shorts/bf16):
//   0        : Q   [32][2048][64]
//   4194304  : K   [32][2048][64]
//   8388608  : V^T [32][64][2048]
//   12582912 : xq_bf16 [4096][1024]
//   16777216 : xk_bf16 [4096][1024]
//   20971520 : Wq_bf16 [1024][1024]; +1M: Wk; +2M: Wv
//   24117248 : mask bias f32[2][2048] (= 0 or -1e9), 16KB

// ---------------------------------------------------------------------------
// f32 -> bf16 convert (memory-bound) + mask-bias build (block 11264).
// ---------------------------------------------------------------------------
__global__ __launch_bounds__(256) void cvt_bf16(
    const float* __restrict__ xq, const float* __restrict__ xk,
    const float* __restrict__ Wq, const float* __restrict__ Wk,
    const float* __restrict__ Wv, const int* __restrict__ key_mask,
    short* __restrict__ ws)
{
    const int blk = blockIdx.x;
    if (blk >= 11264) {
        float* bias = (float*)(ws + 24117248u);
        const int i0 = threadIdx.x * 4;
#pragma unroll
        for (int p = 0; p < 4; ++p) {
            int idx = p * 1024 + i0;          // 0..4095 = mb*2048 + k
            int4 m = *(const int4*)&key_mask[idx];
            f32x4 o = { m.x ? 0.f : -1e9f, m.y ? 0.f : -1e9f,
                        m.z ? 0.f : -1e9f, m.w ? 0.f : -1e9f };
            *(f32x4*)&bias[idx] = o;
        }
        return;
    }
    int seg, local;
    if (blk < 4096)      { seg = 0; local = blk; }
    else if (blk < 8192) { seg = 1; local = blk - 4096; }
    else                 { seg = 2 + ((blk - 8192) >> 10); local = (blk - 8192) & 1023; }
    const float* src = (seg == 0) ? xq : (seg == 1) ? xk
                     : (seg == 2) ? Wq : (seg == 3) ? Wk : Wv;
    const size_t dstoff = (seg == 0) ? 12582912u : (seg == 1) ? 16777216u
                        : 20971520u + (size_t)(seg - 2) * 1048576u;
    const size_t idx = (size_t)local * 1024 + threadIdx.x * 4;
    float4 v = *(const float4*)&src[idx];
    bf16x4 o = { f2bf(v.x), f2bf(v.y), f2bf(v.z), f2bf(v.w) };
    *(bf16x4*)&ws[dstoff + idx] = o;
}

// ---------------------------------------------------------------------------
// Projection GEMM (bf16): out = x @ W^T + bias. (unchanged, verified R3-R5)
// z=0: Q -> [bh][t][64]   z=1: K -> [bh][t][64]   z=2: V -> [bh][64][t]
// ---------------------------------------------------------------------------
__global__ __launch_bounds__(256) void proj_gemm(
    short* __restrict__ ws, const float* __restrict__ bq,
    const float* __restrict__ bk, const float* __restrict__ bv)
{
    const int z = blockIdx.z;
    const short* A  = ws + ((z == 0) ? 12582912u : 16777216u);
    const short* Bw = ws + 20971520u + (size_t)z * 1048576u;
    const float* bias = (z == 0) ? bq : (z == 1) ? bk : bv;
    short* out = ws + (size_t)z * 4194304u;

    const int m0 = blockIdx.x * 128;
    const int n0 = blockIdx.y * 128;
    const int tid  = threadIdx.x;
    const int lane = tid & 63;
    const int wid  = tid >> 6;
    const int wr = wid >> 1, wc = wid & 1;
    const int l15 = lane & 15, lhi = lane >> 4;

    __shared__ alignas(16) short SM[17408];

    const int srow = wid * 32 + (lane >> 2);
    const int scol = (lane & 3) * 8;
    const short* aSrc = A  + (size_t)(m0 + srow) * 1024 + scol;
    const short* bSrc = Bw + (size_t)(n0 + srow) * 1024 + scol;

#define PSTAGE(T, BUF) do {                                                    \
    _Pragma("unroll")                                                          \
    for (int i_ = 0; i_ < 2; ++i_) {                                           \
        __builtin_amdgcn_global_load_lds(                                      \
            (const __attribute__((address_space(1))) unsigned*)                \
                (aSrc + (T) * 32 + i_ * 16384),                                \
            (__attribute__((address_space(3))) unsigned*)                      \
                &SM[(BUF) * 8192 + (wid * 32 + i_ * 16) * 32], 16, 0, 0);      \
        __builtin_amdgcn_global_load_lds(                                      \
            (const __attribute__((address_space(1))) unsigned*)                \
                (bSrc + (T) * 32 + i_ * 16384),                                \
            (__attribute__((address_space(3))) unsigned*)                      \
                &SM[(BUF) * 8192 + 4096 + (wid * 32 + i_ * 16) * 32], 16, 0, 0);\
    } } while (0)

    f32x4 acc[4][4] = {};

    PSTAGE(0, 0);
    for (int t = 0; t < 32; ++t) {
        const int buf = t & 1;
        __syncthreads();
        if (t < 31) PSTAGE(t + 1, buf ^ 1);

        const short* SA = &SM[buf * 8192];
        const short* SB = SA + 4096;
        bf16x8 a[4], b[4];
#pragma unroll
        for (int i = 0; i < 4; ++i)
            a[i] = *(const bf16x8*)&SA[(wr * 64 + i * 16 + l15) * 32 + lhi * 8];
#pragma unroll
        for (int j = 0; j < 4; ++j)
            b[j] = *(const bf16x8*)&SB[(wc * 64 + j * 16 + l15) * 32 + lhi * 8];

        if (z == 2) {
#pragma unroll
            for (int i = 0; i < 4; ++i)
#pragma unroll
                for (int j = 0; j < 4; ++j)
                    acc[i][j] = __builtin_amdgcn_mfma_f32_16x16x32_bf16(
                        a[i], b[j], acc[i][j], 0, 0, 0);
        } else {
#pragma unroll
            for (int i = 0; i < 4; ++i)
#pragma unroll
                for (int j = 0; j < 4; ++j)
                    acc[i][j] = __builtin_amdgcn_mfma_f32_16x16x32_bf16(
                        b[j], a[i], acc[i][j], 0, 0, 0);
        }
    }
#undef PSTAGE

    __syncthreads();
    if (z == 2) {
#pragma unroll
        for (int i = 0; i < 4; ++i) {
            int mm = wr * 64 + i * 16 + lhi * 4;
#pragma unroll
            for (int j = 0; j < 4; ++j) {
                int nn = wc * 64 + j * 16 + l15;
                float bval = bias[n0 + nn];
                bf16x4 pk = { f2bf(acc[i][j][0] + bval), f2bf(acc[i][j][1] + bval),
                              f2bf(acc[i][j][2] + bval), f2bf(acc[i][j][3] + bval) };
                *(bf16x4*)&SM[nn * 136 + mm] = pk;
            }
        }
    } else {
#pragma unroll
        for (int i = 0; i < 4; ++i) {
            int mm = wr * 64 + i * 16 + l15;
#pragma unroll
            for (int j = 0; j < 4; ++j) {
                int nnb = wc * 64 + j * 16 + lhi * 4;
                float4 bw = *(const float4*)&bias[n0 + nnb];
                bf16x4 pk = { f2bf(acc[i][j][0] + bw.x), f2bf(acc[i][j][1] + bw.y),
                              f2bf(acc[i][j][2] + bw.z), f2bf(acc[i][j][3] + bw.w) };
                *(bf16x4*)&SM[mm * 136 + nnb] = pk;
            }
        }
    }
    __syncthreads();

    const int bb = m0 >> 11;
    const int mt = m0 & 2047;
#pragma unroll
    for (int p = 0; p < 8; ++p) {
        int id = p * 256 + tid;
        int rr = id >> 4;
        int g  = id & 15;
        bf16x8 v = *(const bf16x8*)&SM[rr * 136 + g * 8];
        if (z == 2) {
            int nn = n0 + rr, h = nn >> 6, d = nn & 63;
            *(bf16x8*)&out[(((size_t)(bb * 16 + h)) * 64 + d) * 2048 + mt + g * 8] = v;
        } else {
            int nn = n0 + g * 8, h = nn >> 6, d = nn & 63;
            *(bf16x8*)&out[(((size_t)(bb * 16 + h)) * 2048 + mt + rr) * 64 + d] = v;
        }
    }
}

// ---------------------------------------------------------------------------
// Flash attention, in-block split-K. 512 thr = 8 waves: wave (qg, ks) handles
// q-rows [qb*128+qg*32, +32) x keys [ks*1024, +1024). Two independent dbuf
// LDS streams (64KB). Online-softmax merge via LDS at the end. Tree max/sum.
// Keeps (R5-verified): mask-as-C-init bias, defer-max, setprio, XOR-swizzled
// K/V staging, grid (bh, qb) XCD locality, shfl_xor(32) pair reductions.
// ---------------------------------------------------------------------------
__device__ inline float pair_max(float v) { return fmaxf(v, __shfl_xor(v, 32)); }
__device__ inline float pair_sum(float v) { return v + __shfl_xor(v, 32); }

__global__ __launch_bounds__(512, 4) void attn_fwd(
    const short* __restrict__ Qb, const short* __restrict__ Kb,
    const short* __restrict__ Vtb, const int* __restrict__ key_mask,
    const float* __restrict__ biasArr, float* __restrict__ out)
{
    const int bh = blockIdx.x;        // bh fastest: same-bh blocks -> same XCD
    const int qb = blockIdx.y;
    const int b  = bh >> 4;
    const int h  = bh & 15;
    const int mb = bh & 1;            // (b*H + h) % B, B=2
    const int tid  = threadIdx.x;
    const int lane = tid & 63;
    const int wid  = tid >> 6;        // 0..7
    const int qg   = wid & 3;         // q-group
    const int ks   = wid >> 2;        // k-split half
    const int l31  = lane & 31;
    const int hi   = lane >> 5;

    const size_t base = (size_t)bh * 2048 * 64;
    const int q0 = qb * 128 + qg * 32;
    const int ko = ks * 1024;

    // LDS: 2 streams x dbuf x (K 64x64 | V^T 64x64) = 64KB; merge/transpose
    // regions (4 x 2176 f32 = 34.8KB) overlay after the loop.
    __shared__ alignas(16) char SMEM[65536];
    short* KVbase = (short*)SMEM + ks * 16384;
#define KVS(BUF) (KVbase + (BUF) * 8192)

    const int* km_row = key_mask + mb * 2048;
    const float* bias_row = biasArr + mb * 2048;

    bf16x8 qf[4];
#pragma unroll
    for (int kf = 0; kf < 4; ++kf)
        qf[kf] = *(const bf16x8*)&Qb[base + (size_t)(q0 + l31) * 64 + kf * 16 + hi * 8];

    const int lrow = lane >> 3;
    const int lcol = (lane & 7) ^ (lrow & 7);
    const short* srcK[2];
    const short* srcV[2];
#pragma unroll
    for (int i = 0; i < 2; ++i) {
        int r0 = qg * 16 + i * 8;
        srcK[i] = Kb  + base + (size_t)(ko + r0 + lrow) * 64 + lcol * 8;
        srcV[i] = Vtb + base + (size_t)(r0 + lrow) * 2048 + ko + lcol * 8;
    }

    f32x16 acc[2];
#pragma unroll
    for (int n = 0; n < 2; ++n)
#pragma unroll
        for (int r = 0; r < 16; ++r) acc[n][r] = 0.f;
    float mrun = -1e30f, lrun = 0.f;
    const float SC  = 0.18033688f;    // 0.125 * log2(e)
    const float DTH = 44.3614f;       // 8 / SC : defer-max threshold

#define STAGE(T, BUF)                                                          \
    {                                                                          \
        _Pragma("unroll")                                                      \
        for (int i = 0; i < 2; ++i) {                                          \
            int r0 = qg * 16 + i * 8;                                          \
            __builtin_amdgcn_global_load_lds(                                  \
                (const __attribute__((address_space(1))) unsigned int*)        \
                    (srcK[i] + (size_t)(T) * 4096),                            \
                (__attribute__((address_space(3))) unsigned int*)              \
                    &KVS(BUF)[r0 * 64],                                        \
                16, 0, 0);                                                     \
            __builtin_amdgcn_global_load_lds(                                  \
                (const __attribute__((address_space(1))) unsigned int*)        \
                    (srcV[i] + (size_t)(T) * 64),                              \
                (__attribute__((address_space(3))) unsigned int*)              \
                    &KVS(BUF)[4096 + r0 * 64],                                 \
                16, 0, 0);                                                     \
        }                                                                      \
    }

    STAGE(0, 0);

    for (int t = 0; t < 16; ++t) {
        const int buf = t & 1;
        const int k0 = ko + t * 64;
        __syncthreads();
        if (t < 15) STAGE(t + 1, buf ^ 1);

        // S^T = K*Q^T with C initialized to the mask bias (0 / -1e9).
        const f32x4* bp = (const f32x4*)(bias_row + k0);
        f32x16 sacc[2];
#pragma unroll
        for (int s = 0; s < 2; ++s) {
#pragma unroll
            for (int g = 0; g < 4; ++g) {
                f32x4 bv = bp[s * 8 + g * 2 + hi];
#pragma unroll
                for (int c = 0; c < 4; ++c) sacc[s][g * 4 + c] = bv[c];
            }
        }
        __builtin_amdgcn_s_setprio(1);
#pragma unroll
        for (int s = 0; s < 2; ++s) {
#pragma unroll
            for (int kf = 0; kf < 4; ++kf) {
                int row = s * 32 + l31;
                int xg = ((2 * kf + hi) ^ (row & 7)) * 8;
                bf16x8 kfr = *(const bf16x8*)&KVS(buf)[row * 64 + xg];
                sacc[s] = __builtin_amdgcn_mfma_f32_32x32x16_bf16(
                    kfr, qf[kf], sacc[s], 0, 0, 0);
            }
        }
        __builtin_amdgcn_s_setprio(0);

        // tree max (depth 5) + cross-half
        float tm[16];
#pragma unroll
        for (int i = 0; i < 16; ++i) tm[i] = fmaxf(sacc[0][i], sacc[1][i]);
#pragma unroll
        for (int st = 8; st >= 1; st >>= 1)
#pragma unroll
            for (int i = 0; i < st; ++i) tm[i] = fmaxf(tm[i], tm[i + st]);
        float mx = pair_max(tm[0]);

        if (!__all(mx <= mrun + DTH)) {
            float mnew = fmaxf(mrun, mx);
            float fac  = __builtin_amdgcn_exp2f((mrun - mnew) * SC);
            lrun *= fac;
#pragma unroll
            for (int n = 0; n < 2; ++n)
#pragma unroll
                for (int r = 0; r < 16; ++r) acc[n][r] *= fac;
            mrun = mnew;
        }
        const float msc = mrun * SC;

        float p[2][16];
#pragma unroll
        for (int s = 0; s < 2; ++s)
#pragma unroll
            for (int r = 0; r < 16; ++r)
                p[s][r] = __builtin_amdgcn_exp2f(sacc[s][r] * SC - msc);

        // tree sum (depth 5) + cross-half
        float tsum[16];
#pragma unroll
        for (int i = 0; i < 16; ++i) tsum[i] = p[0][i] + p[1][i];
#pragma unroll
        for (int st = 8; st >= 1; st >>= 1)
#pragma unroll
            for (int i = 0; i < st; ++i) tsum[i] += tsum[i + st];
        lrun += pair_sum(tsum[0]);

        unsigned pk2[2][4][2];
#pragma unroll
        for (int s = 0; s < 2; ++s)
#pragma unroll
            for (int g = 0; g < 4; ++g)
#pragma unroll
                for (int w = 0; w < 2; ++w) {
                    unsigned d;
                    asm("v_cvt_pk_bf16_f32 %0, %1, %2"
                        : "=v"(d)
                        : "v"(p[s][g * 4 + 2 * w]), "v"(p[s][g * 4 + 2 * w + 1]));
                    pk2[s][g][w] = d;
                }

        __builtin_amdgcn_s_setprio(1);
#pragma unroll
        for (int s = 0; s < 2; ++s)
#pragma unroll
            for (int kk = 0; kk < 2; ++kk) {
                unsigned w0 = pk2[s][2 * kk][0],     w1 = pk2[s][2 * kk][1];
                unsigned w2 = pk2[s][2 * kk + 1][0], w3 = pk2[s][2 * kk + 1][1];
                asm("v_permlane32_swap_b32 %0, %1" : "+v"(w0), "+v"(w2));
                asm("v_permlane32_swap_b32 %0, %1" : "+v"(w1), "+v"(w3));
                u32x4 fv = { w0, w1, w2, w3 };
                bf16x8 pf = __builtin_bit_cast(bf16x8, fv);
                int kq = s * 2 + kk;
#pragma unroll
                for (int n = 0; n < 2; ++n) {
                    int row = n * 32 + l31;
                    int xg = ((2 * kq + hi) ^ (row & 7)) * 8;
                    bf16x8 vf = *(const bf16x8*)&KVS(buf)[4096 + row * 64 + xg];
                    acc[n] = __builtin_amdgcn_mfma_f32_32x32x16_bf16(
                        vf, pf, acc[n], 0, 0, 0);
                }
            }
        __builtin_amdgcn_s_setprio(0);
    }
#undef STAGE
#undef KVS

    // ---- split-K merge + epilogue ----
    __syncthreads();                       // (A) all KV reads complete
    float* R = (float*)SMEM + qg * 2176;   // per-qg region: O[64][32] | m | l

    if (ks == 1) {
#pragma unroll
        for (int n = 0; n < 2; ++n)
#pragma unroll
            for (int r = 0; r < 16; ++r) {
                int d = n * 32 + (r & 3) + 8 * (r >> 2) + 4 * hi;
                R[d * 32 + l31] = acc[n][r];
            }
        if (hi == 0) { R[2048 + l31] = mrun; R[2080 + l31] = lrun; }
    }
    __syncthreads();                       // (B) partner data visible

    if (ks == 0) {
        float m1 = R[2048 + l31];
        float l1 = R[2080 + l31];
        float o1[2][16];
#pragma unroll
        for (int n = 0; n < 2; ++n)
#pragma unroll
            for (int r = 0; r < 16; ++r) {
                int d = n * 32 + (r & 3) + 8 * (r >> 2) + 4 * hi;
                o1[n][r] = R[d * 32 + l31];
            }
        float mm = fmaxf(mrun, m1);
        float f0 = __builtin_amdgcn_exp2f((mrun - mm) * SC);
        float f1 = __builtin_amdgcn_exp2f((m1 - mm) * SC);
        float lt = lrun * f0 + l1 * f1;
        float qn = (float)km_row[q0 + l31] / lt;

        // transpose via same region (reads above are in program order first)
#pragma unroll
        for (int n = 0; n < 2; ++n)
#pragma unroll
            for (int r = 0; r < 16; ++r) {
                int d = n * 32 + (r & 3) + 8 * (r >> 2) + 4 * hi;
                R[l31 * 68 + d] = (acc[n][r] * f0 + o1[n][r] * f1) * qn;
            }
        const int l15 = lane & 15, lq = lane >> 4;
#pragma unroll
        for (int rep = 0; rep < 8; ++rep) {
            int qr = rep * 4 + lq;
            f32x4 v = *(const f32x4*)&R[qr * 68 + l15 * 4];
            *(f32x4*)&out[((size_t)b * 2048 + q0 + qr) * 1024 + h * 64 + l15 * 4] = v;
        }
    }
}

extern "C" void kernel_launch(void* const* d_in, const int* in_sizes, int n_in,
                              void* d_out, int out_size, void* d_ws, size_t ws_size,
                              hipStream_t stream) {
    const float* queries = (const float*)d_in[0];
    const float* keys    = (const float*)d_in[1];
    const int*   key_mask= (const int*)d_in[2];
    const float* Wq = (const float*)d_in[3];
    const float* bq = (const float*)d_in[4];
    const float* Wk = (const float*)d_in[5];
    const float* bk = (const float*)d_in[6];
    const float* Wv = (const float*)d_in[7];
    const float* bv = (const float*)d_in[8];
    float* out = (float*)d_out;

    short* ws = (short*)d_ws;
    const float* biasArr = (const float*)(ws + 24117248u);

    cvt_bf16<<<11265, 256, 0, stream>>>(queries, keys, Wq, Wk, Wv, key_mask, ws);

    proj_gemm<<<dim3(32, 8, 3), 256, 0, stream>>>(ws, bq, bk, bv);

    attn_fwd<<<dim3(32, 16), 512, 0, stream>>>(
        ws, ws + 4194304, ws + 2 * 4194304, key_mask, biasArr, out);
}

// Round 7
// 122.207 us; speedup vs baseline: 2.0853x; 1.0041x over previous
//
#include <hip/hip_runtime.h>
#include <hip/hip_bf16.h>

typedef __attribute__((ext_vector_type(8))) short bf16x8;
typedef __attribute__((ext_vector_type(4))) short bf16x4;
typedef __attribute__((ext_vector_type(4))) float f32x4;
typedef __attribute__((ext_vector_type(16))) float f32x16;
typedef __attribute__((ext_vector_type(4))) unsigned u32x4;

__device__ inline short f2bf(float f) {
    unsigned u = __builtin_bit_cast(unsigned, f);
    u += 0x7FFF + ((u >> 16) & 1);   // round-to-nearest-even
    return (short)(u >> 16);
}

// ws layout (units: shorts/bf16):
//   0        : Q   [32][2048][64]
//   4194304  : K   [32][2048][64]
//   8388608  : V^T [32][64][2048]
//   12582912 : xq_bf16 [4096][1024]
//   16777216 : xk_bf16 [4096][1024]
//   20971520 : Wq_bf16 [1024][1024]; +1M: Wk; +2M: Wv
//   24117248 : mask bias f32[2][2048] (= 0 or -1e9), 16KB

// ---------------------------------------------------------------------------
// f32 -> bf16 convert (memory-bound) + mask-bias build (block 11264).
// ---------------------------------------------------------------------------
__global__ __launch_bounds__(256) void cvt_bf16(
    const float* __restrict__ xq, const float* __restrict__ xk,
    const float* __restrict__ Wq, const float* __restrict__ Wk,
    const float* __restrict__ Wv, const int* __restrict__ key_mask,
    short* __restrict__ ws)
{
    const int blk = blockIdx.x;
    if (blk >= 11264) {
        float* bias = (float*)(ws + 24117248u);
        const int i0 = threadIdx.x * 4;
#pragma unroll
        for (int p = 0; p < 4; ++p) {
            int idx = p * 1024 + i0;          // 0..4095 = mb*2048 + k
            int4 m = *(const int4*)&key_mask[idx];
            f32x4 o = { m.x ? 0.f : -1e9f, m.y ? 0.f : -1e9f,
                        m.z ? 0.f : -1e9f, m.w ? 0.f : -1e9f };
            *(f32x4*)&bias[idx] = o;
        }
        return;
    }
    int seg, local;
    if (blk < 4096)      { seg = 0; local = blk; }
    else if (blk < 8192) { seg = 1; local = blk - 4096; }
    else                 { seg = 2 + ((blk - 8192) >> 10); local = (blk - 8192) & 1023; }
    const float* src = (seg == 0) ? xq : (seg == 1) ? xk
                     : (seg == 2) ? Wq : (seg == 3) ? Wk : Wv;
    const size_t dstoff = (seg == 0) ? 12582912u : (seg == 1) ? 16777216u
                        : 20971520u + (size_t)(seg - 2) * 1048576u;
    const size_t idx = (size_t)local * 1024 + threadIdx.x * 4;
    float4 v = *(const float4*)&src[idx];
    bf16x4 o = { f2bf(v.x), f2bf(v.y), f2bf(v.z), f2bf(v.w) };
    *(bf16x4*)&ws[dstoff + idx] = o;
}

// ---------------------------------------------------------------------------
// Projection GEMM (bf16): out = x @ W^T + bias.
// z=0: Q -> [bh][t][64]   z=1: K -> [bh][t][64]   z=2: V -> [bh][64][t]
// R7: 3-buffer LDS, 2-deep prefetch, raw s_barrier + counted vmcnt(4)
// (loads stay in flight across barriers; never drain to 0 in steady state).
// ---------------------------------------------------------------------------
__global__ __launch_bounds__(256) void proj_gemm(
    short* __restrict__ ws, const float* __restrict__ bq,
    const float* __restrict__ bk, const float* __restrict__ bv)
{
    const int z = blockIdx.z;
    const short* A  = ws + ((z == 0) ? 12582912u : 16777216u);
    const short* Bw = ws + 20971520u + (size_t)z * 1048576u;
    const float* bias = (z == 0) ? bq : (z == 1) ? bk : bv;
    short* out = ws + (size_t)z * 4194304u;

    const int m0 = blockIdx.x * 128;
    const int n0 = blockIdx.y * 128;
    const int tid  = threadIdx.x;
    const int lane = tid & 63;
    const int wid  = tid >> 6;
    const int wr = wid >> 1, wc = wid & 1;
    const int l15 = lane & 15, lhi = lane >> 4;

    __shared__ alignas(16) short SM[24576];   // 3 x 8192 staging; epilogue 17408

    const int srow = wid * 32 + (lane >> 2);
    const int scol = (lane & 3) * 8;
    const short* aSrc = A  + (size_t)(m0 + srow) * 1024 + scol;
    const short* bSrc = Bw + (size_t)(n0 + srow) * 1024 + scol;

#define PSTAGE(T, BUF) do {                                                    \
    _Pragma("unroll")                                                          \
    for (int i_ = 0; i_ < 2; ++i_) {                                           \
        __builtin_amdgcn_global_load_lds(                                      \
            (const __attribute__((address_space(1))) unsigned*)                \
                (aSrc + (T) * 32 + i_ * 16384),                                \
            (__attribute__((address_space(3))) unsigned*)                      \
                &SM[(BUF) * 8192 + (wid * 32 + i_ * 16) * 32], 16, 0, 0);      \
        __builtin_amdgcn_global_load_lds(                                      \
            (const __attribute__((address_space(1))) unsigned*)                \
                (bSrc + (T) * 32 + i_ * 16384),                                \
            (__attribute__((address_space(3))) unsigned*)                      \
                &SM[(BUF) * 8192 + 4096 + (wid * 32 + i_ * 16) * 32], 16, 0, 0);\
    } } while (0)

    f32x4 acc[4][4] = {};

    PSTAGE(0, 0);
    PSTAGE(1, 1);
    for (int t = 0; t < 32; ++t) {
        const int buf = t % 3;
        // wait for tile t's 4 loads (2 tiles x 4 loads in flight -> keep 4);
        // last iter drains fully.
        if (t < 31) {
            asm volatile("s_waitcnt vmcnt(4)" ::: "memory");
        } else {
            asm volatile("s_waitcnt vmcnt(0)" ::: "memory");
        }
        __builtin_amdgcn_s_barrier();         // raw: no compiler vmcnt(0) drain
        __builtin_amdgcn_sched_barrier(0);
        if (t < 30) PSTAGE(t + 2, (t + 2) % 3);

        const short* SA = &SM[buf * 8192];
        const short* SB = SA + 4096;
        bf16x8 a[4], b[4];
#pragma unroll
        for (int i = 0; i < 4; ++i)
            a[i] = *(const bf16x8*)&SA[(wr * 64 + i * 16 + l15) * 32 + lhi * 8];
#pragma unroll
        for (int j = 0; j < 4; ++j)
            b[j] = *(const bf16x8*)&SB[(wc * 64 + j * 16 + l15) * 32 + lhi * 8];

        if (z == 2) {
#pragma unroll
            for (int i = 0; i < 4; ++i)
#pragma unroll
                for (int j = 0; j < 4; ++j)
                    acc[i][j] = __builtin_amdgcn_mfma_f32_16x16x32_bf16(
                        a[i], b[j], acc[i][j], 0, 0, 0);
        } else {
#pragma unroll
            for (int i = 0; i < 4; ++i)
#pragma unroll
                for (int j = 0; j < 4; ++j)
                    acc[i][j] = __builtin_amdgcn_mfma_f32_16x16x32_bf16(
                        b[j], a[i], acc[i][j], 0, 0, 0);
        }
    }
#undef PSTAGE

    __syncthreads();
    if (z == 2) {
#pragma unroll
        for (int i = 0; i < 4; ++i) {
            int mm = wr * 64 + i * 16 + lhi * 4;
#pragma unroll
            for (int j = 0; j < 4; ++j) {
                int nn = wc * 64 + j * 16 + l15;
                float bval = bias[n0 + nn];
                bf16x4 pk = { f2bf(acc[i][j][0] + bval), f2bf(acc[i][j][1] + bval),
                              f2bf(acc[i][j][2] + bval), f2bf(acc[i][j][3] + bval) };
                *(bf16x4*)&SM[nn * 136 + mm] = pk;
            }
        }
    } else {
#pragma unroll
        for (int i = 0; i < 4; ++i) {
            int mm = wr * 64 + i * 16 + l15;
#pragma unroll
            for (int j = 0; j < 4; ++j) {
                int nnb = wc * 64 + j * 16 + lhi * 4;
                float4 bw = *(const float4*)&bias[n0 + nnb];
                bf16x4 pk = { f2bf(acc[i][j][0] + bw.x), f2bf(acc[i][j][1] + bw.y),
                              f2bf(acc[i][j][2] + bw.z), f2bf(acc[i][j][3] + bw.w) };
                *(bf16x4*)&SM[mm * 136 + nnb] = pk;
            }
        }
    }
    __syncthreads();

    const int bb = m0 >> 11;
    const int mt = m0 & 2047;
#pragma unroll
    for (int p = 0; p < 8; ++p) {
        int id = p * 256 + tid;
        int rr = id >> 4;
        int g  = id & 15;
        bf16x8 v = *(const bf16x8*)&SM[rr * 136 + g * 8];
        if (z == 2) {
            int nn = n0 + rr, h = nn >> 6, d = nn & 63;
            *(bf16x8*)&out[(((size_t)(bb * 16 + h)) * 64 + d) * 2048 + mt + g * 8] = v;
        } else {
            int nn = n0 + g * 8, h = nn >> 6, d = nn & 63;
            *(bf16x8*)&out[(((size_t)(bb * 16 + h)) * 2048 + mt + rr) * 64 + d] = v;
        }
    }
}

// ---------------------------------------------------------------------------
// Flash attention, in-block split-K (unchanged, R6-verified). 512 thr = 8
// waves: wave (qg, ks) handles q-rows [qb*128+qg*32,+32) x keys [ks*1024,+1024).
// ---------------------------------------------------------------------------
__device__ inline float pair_max(float v) { return fmaxf(v, __shfl_xor(v, 32)); }
__device__ inline float pair_sum(float v) { return v + __shfl_xor(v, 32); }

__global__ __launch_bounds__(512, 4) void attn_fwd(
    const short* __restrict__ Qb, const short* __restrict__ Kb,
    const short* __restrict__ Vtb, const int* __restrict__ key_mask,
    const float* __restrict__ biasArr, float* __restrict__ out)
{
    const int bh = blockIdx.x;        // bh fastest: same-bh blocks -> same XCD
    const int qb = blockIdx.y;
    const int b  = bh >> 4;
    const int h  = bh & 15;
    const int mb = bh & 1;            // (b*H + h) % B, B=2
    const int tid  = threadIdx.x;
    const int lane = tid & 63;
    const int wid  = tid >> 6;        // 0..7
    const int qg   = wid & 3;         // q-group
    const int ks   = wid >> 2;        // k-split half
    const int l31  = lane & 31;
    const int hi   = lane >> 5;

    const size_t base = (size_t)bh * 2048 * 64;
    const int q0 = qb * 128 + qg * 32;
    const int ko = ks * 1024;

    __shared__ alignas(16) char SMEM[65536];
    short* KVbase = (short*)SMEM + ks * 16384;
#define KVS(BUF) (KVbase + (BUF) * 8192)

    const int* km_row = key_mask + mb * 2048;
    const float* bias_row = biasArr + mb * 2048;

    bf16x8 qf[4];
#pragma unroll
    for (int kf = 0; kf < 4; ++kf)
        qf[kf] = *(const bf16x8*)&Qb[base + (size_t)(q0 + l31) * 64 + kf * 16 + hi * 8];

    const int lrow = lane >> 3;
    const int lcol = (lane & 7) ^ (lrow & 7);
    const short* srcK[2];
    const short* srcV[2];
#pragma unroll
    for (int i = 0; i < 2; ++i) {
        int r0 = qg * 16 + i * 8;
        srcK[i] = Kb  + base + (size_t)(ko + r0 + lrow) * 64 + lcol * 8;
        srcV[i] = Vtb + base + (size_t)(r0 + lrow) * 2048 + ko + lcol * 8;
    }

    f32x16 acc[2];
#pragma unroll
    for (int n = 0; n < 2; ++n)
#pragma unroll
        for (int r = 0; r < 16; ++r) acc[n][r] = 0.f;
    float mrun = -1e30f, lrun = 0.f;
    const float SC  = 0.18033688f;    // 0.125 * log2(e)
    const float DTH = 44.3614f;       // 8 / SC : defer-max threshold

#define STAGE(T, BUF)                                                          \
    {                                                                          \
        _Pragma("unroll")                                                      \
        for (int i = 0; i < 2; ++i) {                                          \
            int r0 = qg * 16 + i * 8;                                          \
            __builtin_amdgcn_global_load_lds(                                  \
                (const __attribute__((address_space(1))) unsigned int*)        \
                    (srcK[i] + (size_t)(T) * 4096),                            \
                (__attribute__((address_space(3))) unsigned int*)              \
                    &KVS(BUF)[r0 * 64],                                        \
                16, 0, 0);                                                     \
            __builtin_amdgcn_global_load_lds(                                  \
                (const __attribute__((address_space(1))) unsigned int*)        \
                    (srcV[i] + (size_t)(T) * 64),                              \
                (__attribute__((address_space(3))) unsigned int*)              \
                    &KVS(BUF)[4096 + r0 * 64],                                 \
                16, 0, 0);                                                     \
        }                                                                      \
    }

    STAGE(0, 0);

    for (int t = 0; t < 16; ++t) {
        const int buf = t & 1;
        const int k0 = ko + t * 64;
        __syncthreads();
        if (t < 15) STAGE(t + 1, buf ^ 1);

        const f32x4* bp = (const f32x4*)(bias_row + k0);
        f32x16 sacc[2];
#pragma unroll
        for (int s = 0; s < 2; ++s) {
#pragma unroll
            for (int g = 0; g < 4; ++g) {
                f32x4 bv = bp[s * 8 + g * 2 + hi];
#pragma unroll
                for (int c = 0; c < 4; ++c) sacc[s][g * 4 + c] = bv[c];
            }
        }
        __builtin_amdgcn_s_setprio(1);
#pragma unroll
        for (int s = 0; s < 2; ++s) {
#pragma unroll
            for (int kf = 0; kf < 4; ++kf) {
                int row = s * 32 + l31;
                int xg = ((2 * kf + hi) ^ (row & 7)) * 8;
                bf16x8 kfr = *(const bf16x8*)&KVS(buf)[row * 64 + xg];
                sacc[s] = __builtin_amdgcn_mfma_f32_32x32x16_bf16(
                    kfr, qf[kf], sacc[s], 0, 0, 0);
            }
        }
        __builtin_amdgcn_s_setprio(0);

        float tm[16];
#pragma unroll
        for (int i = 0; i < 16; ++i) tm[i] = fmaxf(sacc[0][i], sacc[1][i]);
#pragma unroll
        for (int st = 8; st >= 1; st >>= 1)
#pragma unroll
            for (int i = 0; i < st; ++i) tm[i] = fmaxf(tm[i], tm[i + st]);
        float mx = pair_max(tm[0]);

        if (!__all(mx <= mrun + DTH)) {
            float mnew = fmaxf(mrun, mx);
            float fac  = __builtin_amdgcn_exp2f((mrun - mnew) * SC);
            lrun *= fac;
#pragma unroll
            for (int n = 0; n < 2; ++n)
#pragma unroll
                for (int r = 0; r < 16; ++r) acc[n][r] *= fac;
            mrun = mnew;
        }
        const float msc = mrun * SC;

        float p[2][16];
#pragma unroll
        for (int s = 0; s < 2; ++s)
#pragma unroll
            for (int r = 0; r < 16; ++r)
                p[s][r] = __builtin_amdgcn_exp2f(sacc[s][r] * SC - msc);

        float tsum[16];
#pragma unroll
        for (int i = 0; i < 16; ++i) tsum[i] = p[0][i] + p[1][i];
#pragma unroll
        for (int st = 8; st >= 1; st >>= 1)
#pragma unroll
            for (int i = 0; i < st; ++i) tsum[i] += tsum[i + st];
        lrun += pair_sum(tsum[0]);

        unsigned pk2[2][4][2];
#pragma unroll
        for (int s = 0; s < 2; ++s)
#pragma unroll
            for (int g = 0; g < 4; ++g)
#pragma unroll
                for (int w = 0; w < 2; ++w) {
                    unsigned d;
                    asm("v_cvt_pk_bf16_f32 %0, %1, %2"
                        : "=v"(d)
                        : "v"(p[s][g * 4 + 2 * w]), "v"(p[s][g * 4 + 2 * w + 1]));
                    pk2[s][g][w] = d;
                }

        __builtin_amdgcn_s_setprio(1);
#pragma unroll
        for (int s = 0; s < 2; ++s)
#pragma unroll
            for (int kk = 0; kk < 2; ++kk) {
                unsigned w0 = pk2[s][2 * kk][0],     w1 = pk2[s][2 * kk][1];
                unsigned w2 = pk2[s][2 * kk + 1][0], w3 = pk2[s][2 * kk + 1][1];
                asm("v_permlane32_swap_b32 %0, %1" : "+v"(w0), "+v"(w2));
                asm("v_permlane32_swap_b32 %0, %1" : "+v"(w1), "+v"(w3));
                u32x4 fv = { w0, w1, w2, w3 };
                bf16x8 pf = __builtin_bit_cast(bf16x8, fv);
                int kq = s * 2 + kk;
#pragma unroll
                for (int n = 0; n < 2; ++n) {
                    int row = n * 32 + l31;
                    int xg = ((2 * kq + hi) ^ (row & 7)) * 8;
                    bf16x8 vf = *(const bf16x8*)&KVS(buf)[4096 + row * 64 + xg];
                    acc[n] = __builtin_amdgcn_mfma_f32_32x32x16_bf16(
                        vf, pf, acc[n], 0, 0, 0);
                }
            }
        __builtin_amdgcn_s_setprio(0);
    }
#undef STAGE
#undef KVS

    // ---- split-K merge + epilogue ----
    __syncthreads();                       // (A) all KV reads complete
    float* R = (float*)SMEM + qg * 2176;   // per-qg region: O[64][32] | m | l

    if (ks == 1) {
#pragma unroll
        for (int n = 0; n < 2; ++n)
#pragma unroll
            for (int r = 0; r < 16; ++r) {
                int d = n * 32 + (r & 3) + 8 * (r >> 2) + 4 * hi;
                R[d * 32 + l31] = acc[n][r];
            }
        if (hi == 0) { R[2048 + l31] = mrun; R[2080 + l31] = lrun; }
    }
    __syncthreads();                       // (B) partner data visible

    if (ks == 0) {
        float m1 = R[2048 + l31];
        float l1 = R[2080 + l31];
        float o1[2][16];
#pragma unroll
        for (int n = 0; n < 2; ++n)
#pragma unroll
            for (int r = 0; r < 16; ++r) {
                int d = n * 32 + (r & 3) + 8 * (r >> 2) + 4 * hi;
                o1[n][r] = R[d * 32 + l31];
            }
        float mm = fmaxf(mrun, m1);
        float f0 = __builtin_amdgcn_exp2f((mrun - mm) * SC);
        float f1 = __builtin_amdgcn_exp2f((m1 - mm) * SC);
        float lt = lrun * f0 + l1 * f1;
        float qn = (float)km_row[q0 + l31] / lt;

#pragma unroll
        for (int n = 0; n < 2; ++n)
#pragma unroll
            for (int r = 0; r < 16; ++r) {
                int d = n * 32 + (r & 3) + 8 * (r >> 2) + 4 * hi;
                R[l31 * 68 + d] = (acc[n][r] * f0 + o1[n][r] * f1) * qn;
            }
        const int l15 = lane & 15, lq = lane >> 4;
#pragma unroll
        for (int rep = 0; rep < 8; ++rep) {
            int qr = rep * 4 + lq;
            f32x4 v = *(const f32x4*)&R[qr * 68 + l15 * 4];
            *(f32x4*)&out[((size_t)b * 2048 + q0 + qr) * 1024 + h * 64 + l15 * 4] = v;
        }
    }
}

extern "C" void kernel_launch(void* const* d_in, const int* in_sizes, int n_in,
                              void* d_out, int out_size, void* d_ws, size_t ws_size,
                              hipStream_t stream) {
    const float* queries = (const float*)d_in[0];
    const float* keys    = (const float*)d_in[1];
    const int*   key_mask= (const int*)d_in[2];
    const float* Wq = (const float*)d_in[3];
    const float* bq = (const float*)d_in[4];
    const float* Wk = (const float*)d_in[5];
    const float* bk = (const float*)d_in[6];
    const float* Wv = (const float*)d_in[7];
    const float* bv = (const float*)d_in[8];
    float* out = (float*)d_out;

    short* ws = (short*)d_ws;
    const float* biasArr = (const float*)(ws + 24117248u);

    cvt_bf16<<<11265, 256, 0, stream>>>(queries, keys, Wq, Wk, Wv, key_mask, ws);

    proj_gemm<<<dim3(32, 8, 3), 256, 0, stream>>>(ws, bq, bk, bv);

    attn_fwd<<<dim3(32, 16), 512, 0, stream>>>(
        ws, ws + 4194304, ws + 2 * 4194304, key_mask, biasArr, out);
}